// Round 1
// baseline (1147.693 us; speedup 1.0000x reference)
//
#include <hip/hip_runtime.h>
#include <hip/hip_bf16.h>

typedef __hip_bfloat16 bf16;

// Problem constants (fixed by setup_inputs)
constexpr int NB  = 32;     // B: graphs
constexpr int NM  = 256;    // N_MAX nodes/graph
constexpr int DD  = 256;    // hidden
constexpr int NH  = 8;      // heads
constexpr int DH  = 32;     // head dim
constexpr int QP  = 64;     // Q*P
constexpr int FF  = 32;     // phi hidden
constexpr int NT  = NB * NM;       // 8192 nodes
constexpr int HD2 = NT * DD;       // 2097152 floats (h / o buffers)
constexpr float QSCALE = 0.17677669529663687f;  // 1/sqrt(32)

// ---------------------------------------------------------------- init: h=x, out_z=z
__global__ __launch_bounds__(256) void k_init(const float* __restrict__ x,
                                              const float* __restrict__ z,
                                              float* __restrict__ h,
                                              float* __restrict__ outz) {
  int idx = blockIdx.x * 256 + threadIdx.x;               // 524288 float4s
  const float4* x4 = (const float4*)x;
  float4* h4 = (float4*)h;
  h4[idx] = x4[idx];
  if (idx < (NT * QP * 2) / 4) {                          // 262144 float4s of z
    ((float4*)outz)[idx] = ((const float4*)z)[idx];
  }
}

// ---------------------------------------------------------------- phi(Lambda): [B,H,QP]
__global__ __launch_bounds__(256) void k_phi(const float* __restrict__ Lam,
                                             const float* __restrict__ W1,
                                             const float* __restrict__ b1,
                                             const float* __restrict__ W2,
                                             const float* __restrict__ b2,
                                             float* __restrict__ phi, int l) {
  int t = blockIdx.x * 256 + threadIdx.x;                 // B*QP = 2048
  if (t >= NB * QP) return;
  int b = t >> 6, qp = t & 63;
  float lam = Lam[b * QP + qp];
  const float* w1 = W1 + l * FF;
  const float* bb1 = b1 + l * FF;
  const float* w2 = W2 + l * FF * NH;
  const float* bb2 = b2 + l * NH;
  float acc[NH];
#pragma unroll
  for (int h = 0; h < NH; ++h) acc[h] = bb2[h];
  for (int f = 0; f < FF; ++f) {
    float a = lam * w1[f] + bb1[f];
    a = a > 0.f ? a : 0.f;
#pragma unroll
    for (int h = 0; h < NH; ++h) acc[h] += a * w2[f * NH + h];
  }
#pragma unroll
  for (int h = 0; h < NH; ++h) phi[(b * NH + h) * QP + qp] = acc[h];
}

// ---------------------------------------------------------------- 64x64 fp32 GEMM tile core
// C[64x64] = A[m0:m0+64, 0:256] @ W[0:256, c0:c0+64], A and W row-major ld=256.
__device__ __forceinline__ void gemm64x64_f32(const float* __restrict__ A,
                                              const float* __restrict__ W,
                                              int m0, int c0, float (&acc)[4][4],
                                              float (&As)[64][33], float (&Bs)[32][65]) {
  const int t = threadIdx.x;
  const int tx = t & 15, ty = t >> 4;
  const int ar = t >> 3, akq = (t & 7) * 4;
  const int bk = t >> 4, bnq = (t & 15) * 4;
  for (int k0 = 0; k0 < 256; k0 += 32) {
    const float4 a0 = *(const float4*)(A + (m0 + ar) * 256 + k0 + akq);
    const float4 a1 = *(const float4*)(A + (m0 + ar + 32) * 256 + k0 + akq);
    const float4 w0 = *(const float4*)(W + (k0 + bk) * 256 + c0 + bnq);
    const float4 w1 = *(const float4*)(W + (k0 + bk + 16) * 256 + c0 + bnq);
    __syncthreads();
    As[ar][akq + 0] = a0.x; As[ar][akq + 1] = a0.y; As[ar][akq + 2] = a0.z; As[ar][akq + 3] = a0.w;
    As[ar + 32][akq + 0] = a1.x; As[ar + 32][akq + 1] = a1.y; As[ar + 32][akq + 2] = a1.z; As[ar + 32][akq + 3] = a1.w;
    Bs[bk][bnq + 0] = w0.x; Bs[bk][bnq + 1] = w0.y; Bs[bk][bnq + 2] = w0.z; Bs[bk][bnq + 3] = w0.w;
    Bs[bk + 16][bnq + 0] = w1.x; Bs[bk + 16][bnq + 1] = w1.y; Bs[bk + 16][bnq + 2] = w1.z; Bs[bk + 16][bnq + 3] = w1.w;
    __syncthreads();
#pragma unroll 8
    for (int k = 0; k < 32; ++k) {
      float av0 = As[ty * 4 + 0][k], av1 = As[ty * 4 + 1][k];
      float av2 = As[ty * 4 + 2][k], av3 = As[ty * 4 + 3][k];
      float bv0 = Bs[k][tx * 4 + 0], bv1 = Bs[k][tx * 4 + 1];
      float bv2 = Bs[k][tx * 4 + 2], bv3 = Bs[k][tx * 4 + 3];
      acc[0][0] += av0 * bv0; acc[0][1] += av0 * bv1; acc[0][2] += av0 * bv2; acc[0][3] += av0 * bv3;
      acc[1][0] += av1 * bv0; acc[1][1] += av1 * bv1; acc[1][2] += av1 * bv2; acc[1][3] += av1 * bv3;
      acc[2][0] += av2 * bv0; acc[2][1] += av2 * bv1; acc[2][2] += av2 * bv2; acc[2][3] += av2 * bv3;
      acc[3][0] += av3 * bv0; acc[3][1] += av3 * bv1; acc[3][2] += av3 * bv2; acc[3][3] += av3 * bv3;
    }
  }
}

// ---------------------------------------------------------------- QKV projection
// grid (12, 128): x = 64-col tile over 768 concat cols, y = 64-row tile over 8192 rows
__global__ __launch_bounds__(256) void k_qkv(const float* __restrict__ A,
                                             const float* __restrict__ Wq,
                                             const float* __restrict__ Wk,
                                             const float* __restrict__ Wv,
                                             const float* __restrict__ bq,
                                             const float* __restrict__ bk,
                                             const float* __restrict__ bv,
                                             float* __restrict__ qh, float* __restrict__ kh,
                                             float* __restrict__ vh, int l) {
  __shared__ float As[64][33];
  __shared__ float Bs[32][65];
  const int n0 = blockIdx.x * 64;
  const int m0 = blockIdx.y * 64;
  const int mat = n0 >> 8;          // 0=q 1=k 2=v
  const int c0 = n0 & 255;
  const float* W = (mat == 0 ? Wq : mat == 1 ? Wk : Wv) + l * DD * DD;
  const float* bb = (mat == 0 ? bq : mat == 1 ? bk : bv) + l * DD;
  float* outp = (mat == 0 ? qh : mat == 1 ? kh : vh);
  const float scale = (mat == 0) ? QSCALE : 1.0f;
  float acc[4][4] = {};
  gemm64x64_f32(A, W, m0, c0, acc, As, Bs);
  const int tx = threadIdx.x & 15, ty = threadIdx.x >> 4;
#pragma unroll
  for (int i2 = 0; i2 < 4; ++i2) {
    const int row = m0 + ty * 4 + i2;
    const int b_ = row >> 8, nn = row & 255;
#pragma unroll
    for (int j2 = 0; j2 < 4; ++j2) {
      const int col = c0 + tx * 4 + j2;
      const float v = (acc[i2][j2] + bb[col]) * scale;
      // layout [b][h][n][dh]
      outp[((b_ * NH + (col >> 5)) * NM + nn) * DH + (col & 31)] = v;
    }
  }
}

// ---------------------------------------------------------------- O projection
// grid (4, 128)
__global__ __launch_bounds__(256) void k_oproj(const float* __restrict__ A,
                                               const float* __restrict__ Wo,
                                               const float* __restrict__ bo,
                                               float* __restrict__ outp, int l) {
  __shared__ float As[64][33];
  __shared__ float Bs[32][65];
  const int c0 = blockIdx.x * 64;
  const int m0 = blockIdx.y * 64;
  float acc[4][4] = {};
  gemm64x64_f32(A, Wo + l * DD * DD, m0, c0, acc, As, Bs);
  const float* bb = bo + l * DD;
  const int tx = threadIdx.x & 15, ty = threadIdx.x >> 4;
#pragma unroll
  for (int i2 = 0; i2 < 4; ++i2) {
    const int row = m0 + ty * 4 + i2;
#pragma unroll
    for (int j2 = 0; j2 < 4; ++j2) {
      const int col = c0 + tx * 4 + j2;
      outp[row * DD + col] = acc[i2][j2] + bb[col];
    }
  }
}

// ---------------------------------------------------------------- eigen bias GEMM
// bias[b,h,i,j] = sum_c phi[b,h,c>>1] * z[b,i,c] * z[b,j,c],  c in [0,128) (qp*2+ri)
// grid (16, 256): x = (i-tile*4 + j-tile), y = b*8+h
__global__ __launch_bounds__(256) void k_bias(const float* __restrict__ z,
                                              const float* __restrict__ phi,
                                              bf16* __restrict__ biasb) {
  __shared__ float Az[64][133];
  __shared__ float Bz[64][133];
  const int bh = blockIdx.y;
  const int b = bh >> 3;
  const int i0 = (blockIdx.x >> 2) * 64;
  const int j0 = (blockIdx.x & 3) * 64;
  const float* ph = phi + bh * QP;
  const int t = threadIdx.x;
#pragma unroll
  for (int p = 0; p < 8; ++p) {
    const int idx = p * 256 + t;
    const int r = idx >> 5;
    const int c = (idx & 31) * 4;
    const float w0 = ph[c >> 1];
    const float w1 = ph[(c >> 1) + 1];
    const float4 va = *(const float4*)(z + (size_t)(b * NM + i0 + r) * 128 + c);
    Az[r][c + 0] = va.x * w0; Az[r][c + 1] = va.y * w0;
    Az[r][c + 2] = va.z * w1; Az[r][c + 3] = va.w * w1;
    const float4 vb = *(const float4*)(z + (size_t)(b * NM + j0 + r) * 128 + c);
    Bz[r][c + 0] = vb.x; Bz[r][c + 1] = vb.y; Bz[r][c + 2] = vb.z; Bz[r][c + 3] = vb.w;
  }
  __syncthreads();
  const int tx = t & 15, ty = t >> 4;
  float acc[4][4] = {};
#pragma unroll 4
  for (int c = 0; c < 128; ++c) {
    float a0 = Az[ty * 4 + 0][c], a1 = Az[ty * 4 + 1][c];
    float a2 = Az[ty * 4 + 2][c], a3 = Az[ty * 4 + 3][c];
    float b0 = Bz[tx * 4 + 0][c], b1 = Bz[tx * 4 + 1][c];
    float b2 = Bz[tx * 4 + 2][c], b3 = Bz[tx * 4 + 3][c];
    acc[0][0] += a0 * b0; acc[0][1] += a0 * b1; acc[0][2] += a0 * b2; acc[0][3] += a0 * b3;
    acc[1][0] += a1 * b0; acc[1][1] += a1 * b1; acc[1][2] += a1 * b2; acc[1][3] += a1 * b3;
    acc[2][0] += a2 * b0; acc[2][1] += a2 * b1; acc[2][2] += a2 * b2; acc[2][3] += a2 * b3;
    acc[3][0] += a3 * b0; acc[3][1] += a3 * b1; acc[3][2] += a3 * b2; acc[3][3] += a3 * b3;
  }
  bf16* bp = biasb + (size_t)bh * NM * NM;
#pragma unroll
  for (int i2 = 0; i2 < 4; ++i2)
#pragma unroll
    for (int j2 = 0; j2 < 4; ++j2)
      bp[(i0 + ty * 4 + i2) * NM + j0 + tx * 4 + j2] = (bf16)acc[i2][j2];
}

// ---------------------------------------------------------------- fused attention per (b,h)
// grid 256 = b*8+h; 256 threads. q pre-scaled by 1/sqrt(dh).
__global__ __launch_bounds__(256) void k_attn(const float* __restrict__ qh,
                                              const float* __restrict__ kh,
                                              const float* __restrict__ vh,
                                              const bf16* __restrict__ biasb,
                                              float* __restrict__ ob) {
  __shared__ float Ks[NM][33];
  __shared__ float Vs[NM][33];
  __shared__ float Qs[64][33];
  __shared__ bf16 Ps[64][264];
  __shared__ float rsum[64];
  const int bh = blockIdx.x;
  const int b = bh >> 3, hh = bh & 7;
  const int t = threadIdx.x;
  const float* kp = kh + (size_t)bh * NM * DH;
  const float* vp = vh + (size_t)bh * NM * DH;
  const float* qp = qh + (size_t)bh * NM * DH;
  const bf16* bp = biasb + (size_t)bh * NM * NM;
#pragma unroll
  for (int p = 0; p < 8; ++p) {
    const int idx = p * 256 + t;
    const int r = idx >> 3, dq = (idx & 7) * 4;
    const float4 kv = *(const float4*)(kp + r * DH + dq);
    Ks[r][dq + 0] = kv.x; Ks[r][dq + 1] = kv.y; Ks[r][dq + 2] = kv.z; Ks[r][dq + 3] = kv.w;
    const float4 vv = *(const float4*)(vp + r * DH + dq);
    Vs[r][dq + 0] = vv.x; Vs[r][dq + 1] = vv.y; Vs[r][dq + 2] = vv.z; Vs[r][dq + 3] = vv.w;
  }
  const int tx = t & 15, ty = t >> 4;
  for (int i0 = 0; i0 < NM; i0 += 64) {
    __syncthreads();   // K/V staged (first iter); prev iter's PV done (later iters)
#pragma unroll
    for (int p = 0; p < 2; ++p) {
      const int idx = p * 256 + t;
      const int r = idx >> 3, dq = (idx & 7) * 4;
      const float4 qv = *(const float4*)(qp + (i0 + r) * DH + dq);
      Qs[r][dq + 0] = qv.x; Qs[r][dq + 1] = qv.y; Qs[r][dq + 2] = qv.z; Qs[r][dq + 3] = qv.w;
    }
    __syncthreads();
    // scores: rows i = ty*4+r, cols j = s*16+tx
    float acc[4][16];
#pragma unroll
    for (int r = 0; r < 4; ++r)
#pragma unroll
      for (int s = 0; s < 16; ++s)
        acc[r][s] = (float)bp[(i0 + ty * 4 + r) * NM + s * 16 + tx];
#pragma unroll 4
    for (int k = 0; k < DH; ++k) {
      float a0 = Qs[ty * 4 + 0][k], a1 = Qs[ty * 4 + 1][k];
      float a2 = Qs[ty * 4 + 2][k], a3 = Qs[ty * 4 + 3][k];
#pragma unroll
      for (int s = 0; s < 16; ++s) {
        const float kv = Ks[s * 16 + tx][k];
        acc[0][s] += a0 * kv; acc[1][s] += a1 * kv;
        acc[2][s] += a2 * kv; acc[3][s] += a3 * kv;
      }
    }
    // softmax over j (row spread across the 16 tx lanes of this ty group)
#pragma unroll
    for (int r = 0; r < 4; ++r) {
      float mx = acc[r][0];
#pragma unroll
      for (int s = 1; s < 16; ++s) mx = fmaxf(mx, acc[r][s]);
      mx = fmaxf(mx, __shfl_xor(mx, 1, 16));
      mx = fmaxf(mx, __shfl_xor(mx, 2, 16));
      mx = fmaxf(mx, __shfl_xor(mx, 4, 16));
      mx = fmaxf(mx, __shfl_xor(mx, 8, 16));
      float sm = 0.f;
#pragma unroll
      for (int s = 0; s < 16; ++s) {
        acc[r][s] = __expf(acc[r][s] - mx);
        sm += acc[r][s];
      }
      sm += __shfl_xor(sm, 1, 16);
      sm += __shfl_xor(sm, 2, 16);
      sm += __shfl_xor(sm, 4, 16);
      sm += __shfl_xor(sm, 8, 16);
#pragma unroll
      for (int s = 0; s < 16; ++s) Ps[ty * 4 + r][s * 16 + tx] = (bf16)acc[r][s];
      if (tx == 0) rsum[ty * 4 + r] = 1.0f / sm;
    }
    __syncthreads();
    // PV: thread -> row i = t>>2, d-slice d0 = (t&3)*8
    const int i = t >> 2;
    const int d0 = (t & 3) * 8;
    float o[8] = {};
#pragma unroll 8
    for (int j = 0; j < NM; ++j) {
      const float pv = (float)Ps[i][j];
#pragma unroll
      for (int e = 0; e < 8; ++e) o[e] += pv * Vs[j][d0 + e];
    }
    const float rs = rsum[i];
    float* op_ = ob + (size_t)(b * NM + i0 + i) * DD + hh * DH + d0;
#pragma unroll
    for (int e = 0; e < 8; ++e) op_[e] = o[e] * rs;
  }
}

// ---------------------------------------------------------------- residual + BN stats
// grid 256: block j handles rows [j*32, j*32+32); thread t = column
__global__ __launch_bounds__(256) void k_resbn_stats(const float* __restrict__ op,
                                                     float* __restrict__ h,
                                                     float* __restrict__ accum) {
  const int col = threadIdx.x;
  const int r0 = blockIdx.x * 32;
  float s = 0.f, ss = 0.f;
#pragma unroll 8
  for (int r = 0; r < 32; ++r) {
    const int idx = (r0 + r) * DD + col;
    const float v = op[idx] + h[idx];
    h[idx] = v;
    s += v;
    ss += v * v;
  }
  atomicAdd(&accum[col], s);
  atomicAdd(&accum[DD + col], ss);
}

// ---------------------------------------------------------------- BN apply
__global__ __launch_bounds__(256) void k_bn_apply(const float* __restrict__ h,
                                                  const float* __restrict__ accum,
                                                  const float* __restrict__ gamma,
                                                  const float* __restrict__ beta,
                                                  float* __restrict__ outp, int l) {
  const int idx = blockIdx.x * 256 + threadIdx.x;         // over NT*DD
  const int col = idx & 255;
  const float mean = accum[col] * (1.0f / NT);
  const float var = accum[DD + col] * (1.0f / NT) - mean * mean;
  const float rstd = rsqrtf(var + 1e-5f);
  outp[idx] = (h[idx] - mean) * rstd * gamma[l * DD + col] + beta[l * DD + col];
}

// ================================================================ host
extern "C" void kernel_launch(void* const* d_in, const int* in_sizes, int n_in,
                              void* d_out, int out_size, void* d_ws, size_t ws_size,
                              hipStream_t stream) {
  (void)in_sizes; (void)n_in; (void)out_size; (void)ws_size;
  const float* x    = (const float*)d_in[0];
  const float* z    = (const float*)d_in[1];
  const float* Lam  = (const float*)d_in[2];
  // d_in[3] edge_attr unused
  const float* Wq   = (const float*)d_in[4];
  const float* Wk   = (const float*)d_in[5];
  const float* Wv   = (const float*)d_in[6];
  const float* Wo   = (const float*)d_in[7];
  const float* bq   = (const float*)d_in[8];
  const float* bk   = (const float*)d_in[9];
  const float* bv   = (const float*)d_in[10];
  const float* bo   = (const float*)d_in[11];
  const float* pW1  = (const float*)d_in[12];
  const float* pb1  = (const float*)d_in[13];
  const float* pW2  = (const float*)d_in[14];
  const float* pb2  = (const float*)d_in[15];
  const float* gam  = (const float*)d_in[16];
  const float* bet  = (const float*)d_in[17];
  // d_in[18] edge_index, d_in[19] batch unused (uniform: pos = i & 255)
  float* out = (float*)d_out;

  float* h    = (float*)d_ws;          // NT*DD
  float* qh   = h  + HD2;              // [B][H][NM][DH]
  float* kh   = qh + HD2;
  float* vh   = kh + HD2;
  float* ob   = vh + HD2;              // attention output [NT][DD]
  float* op   = qh;                    // o-projection reuses qh (dead after attn)
  float* phi  = ob + HD2;              // [B][H][QP]
  float* bna  = phi + NB * NH * QP;    // 2*DD accum
  bf16*  bias = (bf16*)(bna + 2 * DD); // [B*H][NM][NM] bf16  (~33.5 MB)

  k_init<<<2048, 256, 0, stream>>>(x, z, h, out + HD2);
  for (int l = 0; l < 4; ++l) {
    k_phi<<<8, 256, 0, stream>>>(Lam, pW1, pb1, pW2, pb2, phi, l);
    k_qkv<<<dim3(12, 128), 256, 0, stream>>>(h, Wq, Wk, Wv, bq, bk, bv, qh, kh, vh, l);
    k_bias<<<dim3(16, 256), 256, 0, stream>>>(z, phi, bias);
    k_attn<<<256, 256, 0, stream>>>(qh, kh, vh, bias, ob);
    k_oproj<<<dim3(4, 128), 256, 0, stream>>>(ob, Wo, bo, op, l);
    hipMemsetAsync(bna, 0, 2 * DD * sizeof(float), stream);
    k_resbn_stats<<<256, 256, 0, stream>>>(op, h, bna);
    k_bn_apply<<<8192, 256, 0, stream>>>(h, bna, gam, bet, (l == 3 ? out : h), l);
  }
}

// Round 2
// 543.349 us; speedup vs baseline: 2.1123x; 2.1123x over previous
//
#include <hip/hip_runtime.h>
#include <hip/hip_bf16.h>

typedef __hip_bfloat16 bf16;
typedef __attribute__((ext_vector_type(8))) short short8v;   // 8 bf16 (4 VGPRs)
typedef __attribute__((ext_vector_type(4))) float f32x4;

constexpr int NB  = 32;
constexpr int NM  = 256;
constexpr int DD  = 256;
constexpr int NH  = 8;
constexpr int QP  = 64;
constexpr int FF  = 32;
constexpr int NT  = NB * NM;        // 8192
constexpr int HD2 = NT * DD;        // 2097152
constexpr float QSCALE = 0.17677669529663687f;

__device__ __forceinline__ float b2f(unsigned short u) {
  return __uint_as_float(((unsigned)u) << 16);
}
__device__ __forceinline__ short f2b(float f) {
  union { bf16 h; short s; } u;
  u.h = __float2bfloat16(f);
  return u.s;
}

// ---------------------------------------------------------------- init: h=x (f32+bf16), out_z=z
__global__ __launch_bounds__(256) void k_init(const float* __restrict__ x,
                                              const float* __restrict__ z,
                                              float* __restrict__ h,
                                              short* __restrict__ hbf,
                                              float* __restrict__ outz) {
  int idx = blockIdx.x * 256 + threadIdx.x;               // 524288 float4s
  float4 v = ((const float4*)x)[idx];
  ((float4*)h)[idx] = v;
  short4 s;
  s.x = f2b(v.x); s.y = f2b(v.y); s.z = f2b(v.z); s.w = f2b(v.w);
  ((short4*)hbf)[idx] = s;
  if (idx < (NT * QP * 2) / 4)
    ((float4*)outz)[idx] = ((const float4*)z)[idx];
}

// ---------------------------------------------------------------- W^T precompute (bf16)
// Wt[mat][j][k] = W[l][k][j]; mat = l*4 + {0:q,1:k,2:v,3:o}. grid (16, 8)
__global__ __launch_bounds__(256) void k_wt(const float* __restrict__ Wq,
                                            const float* __restrict__ Wk,
                                            const float* __restrict__ Wv,
                                            const float* __restrict__ Wo,
                                            short* __restrict__ Wt) {
  __shared__ float Ts[32][33];
  const int mat = blockIdx.x;
  const int l = mat >> 2, wsel = mat & 3;
  const float* W = (wsel == 0 ? Wq : wsel == 1 ? Wk : wsel == 2 ? Wv : Wo) + l * DD * DD;
  const int j0 = blockIdx.y * 32;
  short* out = Wt + (size_t)mat * DD * DD;
  const int t = threadIdx.x;
  const int jj = t & 31, kk8 = t >> 5;
  for (int k0 = 0; k0 < DD; k0 += 32) {
    __syncthreads();
#pragma unroll
    for (int s = 0; s < 4; ++s) {
      const int kl = s * 8 + kk8;
      Ts[kl][jj] = W[(k0 + kl) * DD + j0 + jj];
    }
    __syncthreads();
#pragma unroll
    for (int s = 0; s < 4; ++s) {
      const int jl = (t >> 5) + s * 8;
      const int kl = t & 31;
      out[(size_t)(j0 + jl) * DD + k0 + kl] = f2b(Ts[kl][jl]);
    }
  }
}

// ---------------------------------------------------------------- phi(Lambda): [B,H,QP]
__global__ __launch_bounds__(256) void k_phi(const float* __restrict__ Lam,
                                             const float* __restrict__ W1,
                                             const float* __restrict__ b1,
                                             const float* __restrict__ W2,
                                             const float* __restrict__ b2,
                                             float* __restrict__ phi, int l) {
  int t = blockIdx.x * 256 + threadIdx.x;
  if (t >= NB * QP) return;
  int b = t >> 6, qp = t & 63;
  float lam = Lam[b * QP + qp];
  const float* w1 = W1 + l * FF;
  const float* bb1 = b1 + l * FF;
  const float* w2 = W2 + l * FF * NH;
  const float* bb2 = b2 + l * NH;
  float acc[NH];
#pragma unroll
  for (int h = 0; h < NH; ++h) acc[h] = bb2[h];
  for (int f = 0; f < FF; ++f) {
    float a = lam * w1[f] + bb1[f];
    a = a > 0.f ? a : 0.f;
#pragma unroll
    for (int h = 0; h < NH; ++h) acc[h] += a * w2[f * NH + h];
  }
#pragma unroll
  for (int h = 0; h < NH; ++h) phi[(b * NH + h) * QP + qp] = acc[h];
}

// ---------------------------------------------------------------- MFMA projection GEMM
// C[8192,256] = Abf[8192,256] @ W, W given as Wt (bf16, [j][k]).
// grid (64, 2, nz). 256 thr = 4 waves at 2x2, each wave 64x64 (4x4 frags of 16x16).
__global__ __launch_bounds__(256) void k_proj(const short* __restrict__ Abf,
                                              const short* __restrict__ WtL,   // layer base (4 mats)
                                              const float* __restrict__ b0,
                                              const float* __restrict__ b1,
                                              const float* __restrict__ b2,
                                              short* __restrict__ o0,
                                              short* __restrict__ o1,
                                              short* __restrict__ o2,
                                              float* __restrict__ outf,        // !=null: fp32 single-matrix mode
                                              int matofs, float scale0) {
  __shared__ __align__(16) short As[128 * 128];
  __shared__ __align__(16) short Bs[128 * 128];
  const int t = threadIdx.x;
  const int m0 = blockIdx.x * 128;
  const int j0 = blockIdx.y * 128;
  const int zz = blockIdx.z;
  const short* W = WtL + (size_t)(matofs + zz) * DD * DD;
  const float* bb = zz == 0 ? b0 : zz == 1 ? b1 : b2;
  short* obf = zz == 0 ? o0 : zz == 1 ? o1 : o2;
  const float scale = (zz == 0) ? scale0 : 1.0f;

  const int lane = t & 63, w = t >> 6;
  const int wr = w >> 1, wc = w & 1;
  const int fr = lane & 15, fq = lane >> 4;

  f32x4 acc[4][4] = {};

  for (int kb = 0; kb < 2; ++kb) {
    __syncthreads();
#pragma unroll
    for (int p = 0; p < 8; ++p) {
      const int c = p * 256 + t;
      const int r = c >> 4, ch = c & 15;
      const int sw = ((ch ^ (r & 7)) << 4);
      *(short8v*)((char*)As + r * 256 + sw) =
          *(const short8v*)(Abf + (size_t)(m0 + r) * 256 + kb * 128 + ch * 8);
      *(short8v*)((char*)Bs + r * 256 + sw) =
          *(const short8v*)(W + (size_t)(j0 + r) * 256 + kb * 128 + ch * 8);
    }
    __syncthreads();
#pragma unroll
    for (int ks = 0; ks < 4; ++ks) {
      short8v a[4], bfrag[4];
#pragma unroll
      for (int m = 0; m < 4; ++m) {
        const int rA = wr * 64 + m * 16 + fr;
        a[m] = *(const short8v*)((const char*)As + rA * 256 + (((ks * 4 + fq) ^ (rA & 7)) << 4));
        const int rB = wc * 64 + m * 16 + fr;
        bfrag[m] = *(const short8v*)((const char*)Bs + rB * 256 + (((ks * 4 + fq) ^ (rB & 7)) << 4));
      }
#pragma unroll
      for (int m = 0; m < 4; ++m)
#pragma unroll
        for (int n = 0; n < 4; ++n)
          acc[m][n] = __builtin_amdgcn_mfma_f32_16x16x32_bf16(a[m], bfrag[n], acc[m][n], 0, 0, 0);
    }
  }
#pragma unroll
  for (int n = 0; n < 4; ++n) {
    const int col = j0 + wc * 64 + n * 16 + fr;
    const float bv = bb[col];
#pragma unroll
    for (int m = 0; m < 4; ++m) {
#pragma unroll
      for (int rr = 0; rr < 4; ++rr) {
        const int row = m0 + wr * 64 + m * 16 + fq * 4 + rr;
        const float v = (acc[m][n][rr] + bv) * scale;
        if (outf) outf[(size_t)row * 256 + col] = v;
        else obf[(size_t)row * 256 + col] = f2b(v);
      }
    }
  }
}

// ---------------------------------------------------------------- MFMA eigen-bias GEMM
// bias[bh] = Aw @ z^T per (b,h): Aw[i][c] = z[b,i,c]*phi[bh][c>>1], K=128.
// grid (4, 256): x = 2x2 tile of 128, y = bh.
__global__ __launch_bounds__(256) void k_bias_mfma(const float* __restrict__ z,
                                                   const float* __restrict__ phi,
                                                   bf16* __restrict__ biasb) {
  __shared__ __align__(16) short As[128 * 128];
  __shared__ __align__(16) short Bs[128 * 128];
  const int t = threadIdx.x;
  const int bh = blockIdx.y;
  const int b = bh >> 3;
  const int i0 = (blockIdx.x >> 1) * 128;
  const int j0 = (blockIdx.x & 1) * 128;
  const float* ph = phi + bh * QP;

#pragma unroll
  for (int p = 0; p < 8; ++p) {
    const int c = p * 256 + t;
    const int r = c >> 4, ch = c & 15;
    const int sw = ((ch ^ (r & 7)) << 4);
    const float w0 = ph[ch * 4 + 0], w1 = ph[ch * 4 + 1];
    const float w2 = ph[ch * 4 + 2], w3 = ph[ch * 4 + 3];
    {
      const float* src = z + (size_t)(b * NM + i0 + r) * 128 + ch * 8;
      const float4 v0 = *(const float4*)src;
      const float4 v1 = *(const float4*)(src + 4);
      short8v o;
      o[0] = f2b(v0.x * w0); o[1] = f2b(v0.y * w0); o[2] = f2b(v0.z * w1); o[3] = f2b(v0.w * w1);
      o[4] = f2b(v1.x * w2); o[5] = f2b(v1.y * w2); o[6] = f2b(v1.z * w3); o[7] = f2b(v1.w * w3);
      *(short8v*)((char*)As + r * 256 + sw) = o;
    }
    {
      const float* src = z + (size_t)(b * NM + j0 + r) * 128 + ch * 8;
      const float4 v0 = *(const float4*)src;
      const float4 v1 = *(const float4*)(src + 4);
      short8v o;
      o[0] = f2b(v0.x); o[1] = f2b(v0.y); o[2] = f2b(v0.z); o[3] = f2b(v0.w);
      o[4] = f2b(v1.x); o[5] = f2b(v1.y); o[6] = f2b(v1.z); o[7] = f2b(v1.w);
      *(short8v*)((char*)Bs + r * 256 + sw) = o;
    }
  }
  __syncthreads();

  const int lane = t & 63, w = t >> 6;
  const int wr = w >> 1, wc = w & 1;
  const int fr = lane & 15, fq = lane >> 4;
  f32x4 acc[4][4] = {};
#pragma unroll
  for (int ks = 0; ks < 4; ++ks) {
    short8v a[4], bfrag[4];
#pragma unroll
    for (int m = 0; m < 4; ++m) {
      const int rA = wr * 64 + m * 16 + fr;
      a[m] = *(const short8v*)((const char*)As + rA * 256 + (((ks * 4 + fq) ^ (rA & 7)) << 4));
      const int rB = wc * 64 + m * 16 + fr;
      bfrag[m] = *(const short8v*)((const char*)Bs + rB * 256 + (((ks * 4 + fq) ^ (rB & 7)) << 4));
    }
#pragma unroll
    for (int m = 0; m < 4; ++m)
#pragma unroll
      for (int n = 0; n < 4; ++n)
        acc[m][n] = __builtin_amdgcn_mfma_f32_16x16x32_bf16(a[m], bfrag[n], acc[m][n], 0, 0, 0);
  }
  bf16* bp = biasb + (size_t)bh * NM * NM;
#pragma unroll
  for (int m = 0; m < 4; ++m)
#pragma unroll
    for (int n = 0; n < 4; ++n)
#pragma unroll
      for (int rr = 0; rr < 4; ++rr)
        bp[(size_t)(i0 + wr * 64 + m * 16 + fq * 4 + rr) * NM + j0 + wc * 64 + n * 16 + fr] =
            __float2bfloat16(acc[m][n][rr]);
}

// ---------------------------------------------------------------- fused attention per (b,h)
// q/k/v bf16 [8192][256] (col = h*32+d), q pre-scaled; out bf16 ob same layout.
__global__ __launch_bounds__(256) void k_attn(const short* __restrict__ qh,
                                              const short* __restrict__ kh,
                                              const short* __restrict__ vh,
                                              const bf16* __restrict__ biasb,
                                              short* __restrict__ ob) {
  __shared__ float Ks[NM][33];
  __shared__ float Vs[NM][33];
  __shared__ float Qs[64][33];
  __shared__ bf16 Ps[64][264];
  __shared__ float rsum[64];
  const int bh = blockIdx.x;
  const int b = bh >> 3, hh = bh & 7;
  const int t = threadIdx.x;
  const size_t base = (size_t)(b * NM) * 256 + hh * 32;
  const short* kp = kh + base;
  const short* vp = vh + base;
  const short* qp = qh + base;
  const bf16* bp = biasb + (size_t)bh * NM * NM;
#pragma unroll
  for (int p = 0; p < 4; ++p) {
    const int idx = p * 256 + t;
    const int r = idx >> 2, ch = idx & 3;
    short8v kv = *(const short8v*)(kp + (size_t)r * 256 + ch * 8);
    short8v vv = *(const short8v*)(vp + (size_t)r * 256 + ch * 8);
#pragma unroll
    for (int e = 0; e < 8; ++e) {
      Ks[r][ch * 8 + e] = b2f((unsigned short)kv[e]);
      Vs[r][ch * 8 + e] = b2f((unsigned short)vv[e]);
    }
  }
  const int tx = t & 15, ty = t >> 4;
  for (int i0 = 0; i0 < NM; i0 += 64) {
    __syncthreads();
    {
      const int r = t >> 2, ch = t & 3;
      short8v qv = *(const short8v*)(qp + (size_t)(i0 + r) * 256 + ch * 8);
#pragma unroll
      for (int e = 0; e < 8; ++e) Qs[r][ch * 8 + e] = b2f((unsigned short)qv[e]);
    }
    __syncthreads();
    float acc[4][16];
#pragma unroll
    for (int r = 0; r < 4; ++r)
#pragma unroll
      for (int s = 0; s < 16; ++s)
        acc[r][s] = (float)bp[(size_t)(i0 + ty * 4 + r) * NM + s * 16 + tx];
#pragma unroll 4
    for (int k = 0; k < 32; ++k) {
      float a0 = Qs[ty * 4 + 0][k], a1 = Qs[ty * 4 + 1][k];
      float a2 = Qs[ty * 4 + 2][k], a3 = Qs[ty * 4 + 3][k];
#pragma unroll
      for (int s = 0; s < 16; ++s) {
        const float kv = Ks[s * 16 + tx][k];
        acc[0][s] += a0 * kv; acc[1][s] += a1 * kv;
        acc[2][s] += a2 * kv; acc[3][s] += a3 * kv;
      }
    }
#pragma unroll
    for (int r = 0; r < 4; ++r) {
      float mx = acc[r][0];
#pragma unroll
      for (int s = 1; s < 16; ++s) mx = fmaxf(mx, acc[r][s]);
      mx = fmaxf(mx, __shfl_xor(mx, 1, 16));
      mx = fmaxf(mx, __shfl_xor(mx, 2, 16));
      mx = fmaxf(mx, __shfl_xor(mx, 4, 16));
      mx = fmaxf(mx, __shfl_xor(mx, 8, 16));
      float sm = 0.f;
#pragma unroll
      for (int s = 0; s < 16; ++s) {
        acc[r][s] = __expf(acc[r][s] - mx);
        sm += acc[r][s];
      }
      sm += __shfl_xor(sm, 1, 16);
      sm += __shfl_xor(sm, 2, 16);
      sm += __shfl_xor(sm, 4, 16);
      sm += __shfl_xor(sm, 8, 16);
#pragma unroll
      for (int s = 0; s < 16; ++s) Ps[ty * 4 + r][s * 16 + tx] = (bf16)acc[r][s];
      if (tx == 0) rsum[ty * 4 + r] = 1.0f / sm;
    }
    __syncthreads();
    const int i = t >> 2;
    const int d0 = (t & 3) * 8;
    float o[8] = {};
#pragma unroll 8
    for (int j = 0; j < NM; ++j) {
      const float pv = (float)Ps[i][j];
#pragma unroll
      for (int e = 0; e < 8; ++e) o[e] += pv * Vs[j][d0 + e];
    }
    const float rs = rsum[i];
    short* op_ = ob + (size_t)(b * NM + i0 + i) * 256 + hh * 32 + d0;
#pragma unroll
    for (int e = 0; e < 8; ++e) op_[e] = f2b(o[e] * rs);
  }
}

// ---------------------------------------------------------------- residual + BN stats
__global__ __launch_bounds__(256) void k_resbn_stats(const float* __restrict__ op,
                                                     float* __restrict__ h,
                                                     float* __restrict__ accum) {
  const int col = threadIdx.x;
  const int r0 = blockIdx.x * 32;
  float s = 0.f, ss = 0.f;
#pragma unroll 8
  for (int r = 0; r < 32; ++r) {
    const int idx = (r0 + r) * DD + col;
    const float v = op[idx] + h[idx];
    h[idx] = v;
    s += v;
    ss += v * v;
  }
  atomicAdd(&accum[col], s);
  atomicAdd(&accum[DD + col], ss);
}

// ---------------------------------------------------------------- BN apply (+ bf16 copy)
__global__ __launch_bounds__(256) void k_bn_apply(const float* __restrict__ h,
                                                  const float* __restrict__ accum,
                                                  const float* __restrict__ gamma,
                                                  const float* __restrict__ beta,
                                                  float* __restrict__ outp,
                                                  short* __restrict__ hbf, int l) {
  const int idx = blockIdx.x * 256 + threadIdx.x;
  const int col = idx & 255;
  const float mean = accum[col] * (1.0f / NT);
  const float var = accum[DD + col] * (1.0f / NT) - mean * mean;
  const float rstd = rsqrtf(var + 1e-5f);
  const float v = (h[idx] - mean) * rstd * gamma[l * DD + col] + beta[l * DD + col];
  outp[idx] = v;
  hbf[idx] = f2b(v);
}

// ================================================================ host
extern "C" void kernel_launch(void* const* d_in, const int* in_sizes, int n_in,
                              void* d_out, int out_size, void* d_ws, size_t ws_size,
                              hipStream_t stream) {
  (void)in_sizes; (void)n_in; (void)out_size; (void)ws_size;
  const float* x    = (const float*)d_in[0];
  const float* z    = (const float*)d_in[1];
  const float* Lam  = (const float*)d_in[2];
  const float* Wq   = (const float*)d_in[4];
  const float* Wk   = (const float*)d_in[5];
  const float* Wv   = (const float*)d_in[6];
  const float* Wo   = (const float*)d_in[7];
  const float* bq   = (const float*)d_in[8];
  const float* bk   = (const float*)d_in[9];
  const float* bv   = (const float*)d_in[10];
  const float* bo   = (const float*)d_in[11];
  const float* pW1  = (const float*)d_in[12];
  const float* pb1  = (const float*)d_in[13];
  const float* pW2  = (const float*)d_in[14];
  const float* pb2  = (const float*)d_in[15];
  const float* gam  = (const float*)d_in[16];
  const float* bet  = (const float*)d_in[17];
  float* out = (float*)d_out;

  float* h    = (float*)d_ws;              // 8 MB fp32 running h
  float* op   = h + HD2;                   // 8 MB fp32 o-projection out
  short* hbf  = (short*)(op + HD2);        // 4 MB bf16 h
  short* qbf  = hbf + HD2;                 // 4 MB
  short* kbf  = qbf + HD2;
  short* vbf  = kbf + HD2;
  short* obf  = vbf + HD2;                 // attn out bf16
  short* Wt   = obf + HD2;                 // 2 MB (16 mats x 256x256 bf16)
  float* phi  = (float*)(Wt + 16 * DD * DD);
  float* bna  = phi + NB * NH * QP;
  bf16*  bias = (bf16*)(bna + 2 * DD);     // 33.5 MB

  k_init<<<2048, 256, 0, stream>>>(x, z, h, hbf, out + HD2);
  k_wt<<<dim3(16, 8), 256, 0, stream>>>(Wq, Wk, Wv, Wo, Wt);
  for (int l = 0; l < 4; ++l) {
    k_phi<<<8, 256, 0, stream>>>(Lam, pW1, pb1, pW2, pb2, phi, l);
    k_proj<<<dim3(64, 2, 3), 256, 0, stream>>>(hbf, Wt + (size_t)l * 4 * DD * DD,
                                               bq + l * DD, bk + l * DD, bv + l * DD,
                                               qbf, kbf, vbf, nullptr, 0, QSCALE);
    k_bias_mfma<<<dim3(4, 256), 256, 0, stream>>>(z, phi, bias);
    k_attn<<<256, 256, 0, stream>>>(qbf, kbf, vbf, bias, obf);
    k_proj<<<dim3(64, 2, 1), 256, 0, stream>>>(obf, Wt + (size_t)l * 4 * DD * DD,
                                               bo + l * DD, bo + l * DD, bo + l * DD,
                                               nullptr, nullptr, nullptr, op, 3, 1.0f);
    hipMemsetAsync(bna, 0, 2 * DD * sizeof(float), stream);
    k_resbn_stats<<<256, 256, 0, stream>>>(op, h, bna);
    k_bn_apply<<<8192, 256, 0, stream>>>(h, bna, gam, bet, (l == 3 ? out : h), hbf, l);
  }
}

// Round 3
// 276.301 us; speedup vs baseline: 4.1538x; 1.9665x over previous
//
#include <hip/hip_runtime.h>
#include <hip/hip_bf16.h>

typedef __hip_bfloat16 bf16;
typedef __attribute__((ext_vector_type(8))) short short8v;   // 8 bf16 (4 VGPRs)
typedef __attribute__((ext_vector_type(4))) float f32x4;

constexpr int NB  = 32;
constexpr int NM  = 256;
constexpr int DD  = 256;
constexpr int NH  = 8;
constexpr int QP  = 64;
constexpr int FF  = 32;
constexpr int NT  = NB * NM;        // 8192
constexpr int HD2 = NT * DD;        // 2097152
constexpr float QSCALE = 0.17677669529663687f;

__device__ __forceinline__ float b2f(unsigned short u) {
  return __uint_as_float(((unsigned)u) << 16);
}
__device__ __forceinline__ short f2b(float f) {
  union { bf16 h; short s; } u;
  u.h = __float2bfloat16(f);
  return u.s;
}

// ---------------------------------------------------------------- init: h=x (f32+bf16), out_z=z
__global__ __launch_bounds__(256) void k_init(const float* __restrict__ x,
                                              const float* __restrict__ z,
                                              float* __restrict__ h,
                                              short* __restrict__ hbf,
                                              float* __restrict__ outz) {
  int idx = blockIdx.x * 256 + threadIdx.x;               // 524288 float4s
  float4 v = ((const float4*)x)[idx];
  ((float4*)h)[idx] = v;
  short4 s;
  s.x = f2b(v.x); s.y = f2b(v.y); s.z = f2b(v.z); s.w = f2b(v.w);
  ((short4*)hbf)[idx] = s;
  if (idx < (NT * QP * 2) / 4)
    ((float4*)outz)[idx] = ((const float4*)z)[idx];
}

// ---------------------------------------------------------------- W^T precompute (bf16)
__global__ __launch_bounds__(256) void k_wt(const float* __restrict__ Wq,
                                            const float* __restrict__ Wk,
                                            const float* __restrict__ Wv,
                                            const float* __restrict__ Wo,
                                            short* __restrict__ Wt) {
  __shared__ float Ts[32][33];
  const int mat = blockIdx.x;
  const int l = mat >> 2, wsel = mat & 3;
  const float* W = (wsel == 0 ? Wq : wsel == 1 ? Wk : wsel == 2 ? Wv : Wo) + l * DD * DD;
  const int j0 = blockIdx.y * 32;
  short* out = Wt + (size_t)mat * DD * DD;
  const int t = threadIdx.x;
  const int jj = t & 31, kk8 = t >> 5;
  for (int k0 = 0; k0 < DD; k0 += 32) {
    __syncthreads();
#pragma unroll
    for (int s = 0; s < 4; ++s) {
      const int kl = s * 8 + kk8;
      Ts[kl][jj] = W[(k0 + kl) * DD + j0 + jj];
    }
    __syncthreads();
#pragma unroll
    for (int s = 0; s < 4; ++s) {
      const int jl = (t >> 5) + s * 8;
      const int kl = t & 31;
      out[(size_t)(j0 + jl) * DD + k0 + kl] = f2b(Ts[kl][jl]);
    }
  }
}

// ---------------------------------------------------------------- phi(Lambda): [B,H,QP]
__global__ __launch_bounds__(256) void k_phi(const float* __restrict__ Lam,
                                             const float* __restrict__ W1,
                                             const float* __restrict__ b1,
                                             const float* __restrict__ W2,
                                             const float* __restrict__ b2,
                                             float* __restrict__ phi, int l) {
  int t = blockIdx.x * 256 + threadIdx.x;
  if (t >= NB * QP) return;
  int b = t >> 6, qp = t & 63;
  float lam = Lam[b * QP + qp];
  const float* w1 = W1 + l * FF;
  const float* bb1 = b1 + l * FF;
  const float* w2 = W2 + l * FF * NH;
  const float* bb2 = b2 + l * NH;
  float acc[NH];
#pragma unroll
  for (int h = 0; h < NH; ++h) acc[h] = bb2[h];
  for (int f = 0; f < FF; ++f) {
    float a = lam * w1[f] + bb1[f];
    a = a > 0.f ? a : 0.f;
#pragma unroll
    for (int h = 0; h < NH; ++h) acc[h] += a * w2[f * NH + h];
  }
#pragma unroll
  for (int h = 0; h < NH; ++h) phi[(b * NH + h) * QP + qp] = acc[h];
}

// ---------------------------------------------------------------- MFMA projection GEMM
__global__ __launch_bounds__(256) void k_proj(const short* __restrict__ Abf,
                                              const short* __restrict__ WtL,
                                              const float* __restrict__ b0,
                                              const float* __restrict__ b1,
                                              const float* __restrict__ b2,
                                              short* __restrict__ o0,
                                              short* __restrict__ o1,
                                              short* __restrict__ o2,
                                              float* __restrict__ outf,
                                              int matofs, float scale0) {
  __shared__ __align__(16) short As[128 * 128];
  __shared__ __align__(16) short Bs[128 * 128];
  const int t = threadIdx.x;
  const int m0 = blockIdx.x * 128;
  const int j0 = blockIdx.y * 128;
  const int zz = blockIdx.z;
  const short* W = WtL + (size_t)(matofs + zz) * DD * DD;
  const float* bb = zz == 0 ? b0 : zz == 1 ? b1 : b2;
  short* obf = zz == 0 ? o0 : zz == 1 ? o1 : o2;
  const float scale = (zz == 0) ? scale0 : 1.0f;

  const int lane = t & 63, w = t >> 6;
  const int wr = w >> 1, wc = w & 1;
  const int fr = lane & 15, fq = lane >> 4;

  f32x4 acc[4][4] = {};

  for (int kb = 0; kb < 2; ++kb) {
    __syncthreads();
#pragma unroll
    for (int p = 0; p < 8; ++p) {
      const int c = p * 256 + t;
      const int r = c >> 4, ch = c & 15;
      const int sw = ((ch ^ (r & 7)) << 4);
      *(short8v*)((char*)As + r * 256 + sw) =
          *(const short8v*)(Abf + (size_t)(m0 + r) * 256 + kb * 128 + ch * 8);
      *(short8v*)((char*)Bs + r * 256 + sw) =
          *(const short8v*)(W + (size_t)(j0 + r) * 256 + kb * 128 + ch * 8);
    }
    __syncthreads();
#pragma unroll
    for (int ks = 0; ks < 4; ++ks) {
      short8v a[4], bfrag[4];
#pragma unroll
      for (int m = 0; m < 4; ++m) {
        const int rA = wr * 64 + m * 16 + fr;
        a[m] = *(const short8v*)((const char*)As + rA * 256 + (((ks * 4 + fq) ^ (rA & 7)) << 4));
        const int rB = wc * 64 + m * 16 + fr;
        bfrag[m] = *(const short8v*)((const char*)Bs + rB * 256 + (((ks * 4 + fq) ^ (rB & 7)) << 4));
      }
#pragma unroll
      for (int m = 0; m < 4; ++m)
#pragma unroll
        for (int n = 0; n < 4; ++n)
          acc[m][n] = __builtin_amdgcn_mfma_f32_16x16x32_bf16(a[m], bfrag[n], acc[m][n], 0, 0, 0);
    }
  }
#pragma unroll
  for (int n = 0; n < 4; ++n) {
    const int col = j0 + wc * 64 + n * 16 + fr;
    const float bv = bb[col];
#pragma unroll
    for (int m = 0; m < 4; ++m) {
#pragma unroll
      for (int rr = 0; rr < 4; ++rr) {
        const int row = m0 + wr * 64 + m * 16 + fq * 4 + rr;
        const float v = (acc[m][n][rr] + bv) * scale;
        if (outf) outf[(size_t)row * 256 + col] = v;
        else obf[(size_t)row * 256 + col] = f2b(v);
      }
    }
  }
}

// ---------------------------------------------------------------- fused bias+attention, MFMA
// One block per (b,h), 512 threads = 8 waves, each wave owns 32 q-rows.
// Augmented GEMM: S = Q'K'^T with Q'=[q*scale, phi.z], K'=[k, z], Kdim=160.
// Swapped operands: mfma(A=K'tile, B=Q'^T) -> lane holds S[q=fr][j], softmax in-lane.
__global__ __launch_bounds__(512, 2) void k_attn2(const short* __restrict__ qbf,
                                                  const short* __restrict__ kbf,
                                                  const short* __restrict__ vbf,
                                                  const float* __restrict__ z,
                                                  const float* __restrict__ phi,
                                                  short* __restrict__ obf) {
  __shared__ __align__(16) char Ks[256 * 384];   // K'[256][192 bf16], XOR-swz 16B chunks
  __shared__ __align__(16) char Vt[32 * 512];    // V^T[32][256 bf16], XOR-swz
  __shared__ __align__(16) char Pw[8 * 32 * 80]; // per-wave P tile [32 rows][40 bf16]
  __shared__ float rs_l[8 * 32];
  __shared__ float ph2[128];
  const int t = threadIdx.x;
  const int bh = blockIdx.x;
  const int b = bh >> 3, hh = bh & 7;
  const int bnode = b * 256;

  if (t < 128) ph2[t] = phi[bh * 64 + (t >> 1)];
  {
    const int r = t >> 1, half = t & 1;
    const size_t rowbase = (size_t)(bnode + r) * 256 + hh * 32;
    // K' cols 0..31 = k slice (bf16 direct)
#pragma unroll
    for (int j2 = 0; j2 < 2; ++j2) {
      const int c = half * 2 + j2;
      short8v v = *(const short8v*)(kbf + rowbase + c * 8);
      *(short8v*)(Ks + r * 384 + ((c ^ (r & 7)) << 4)) = v;
    }
    // K' cols 32..159 = z row (fp32 -> bf16)
    const float* zrow = z + (size_t)(bnode + r) * 128 + half * 64;
#pragma unroll
    for (int cc = 0; cc < 8; ++cc) {
      const float4 a0 = *(const float4*)(zrow + cc * 8);
      const float4 a1 = *(const float4*)(zrow + cc * 8 + 4);
      short8v o;
      o[0] = f2b(a0.x); o[1] = f2b(a0.y); o[2] = f2b(a0.z); o[3] = f2b(a0.w);
      o[4] = f2b(a1.x); o[5] = f2b(a1.y); o[6] = f2b(a1.z); o[7] = f2b(a1.w);
      const int c = 4 + half * 8 + cc;
      *(short8v*)(Ks + r * 384 + ((c ^ (r & 7)) << 4)) = o;
    }
    // V^T staging (scalar transpose)
    const short* vrow = vbf + rowbase + half * 16;
    short8v v0 = *(const short8v*)(vrow);
    short8v v1 = *(const short8v*)(vrow + 8);
#pragma unroll
    for (int dd = 0; dd < 16; ++dd) {
      const int d = half * 16 + dd;
      const short val = dd < 8 ? v0[dd] : v1[dd - 8];
      *(short*)(Vt + d * 512 + (((r >> 3) ^ (d & 7)) << 4) + (r & 7) * 2) = val;
    }
  }
  __syncthreads();

  const int lane = t & 63, w = t >> 6;
  const int fr = lane & 15, fq = lane >> 4;
  const int i0w = w * 32;

  // Q' fragments in registers: Qf[s][ks], s = 16-row tile, ks = K-step (5 x 32)
  short8v Qf[2][5];
#pragma unroll
  for (int s = 0; s < 2; ++s) {
    const int node = bnode + i0w + s * 16 + fr;
    Qf[s][0] = *(const short8v*)(qbf + (size_t)node * 256 + hh * 32 + fq * 8);
    const float* zr = z + (size_t)node * 128;
#pragma unroll
    for (int ks = 1; ks < 5; ++ks) {
      const int c0 = (ks - 1) * 32 + fq * 8;
      const float4 a0 = *(const float4*)(zr + c0);
      const float4 a1 = *(const float4*)(zr + c0 + 4);
      short8v o;
      o[0] = f2b(a0.x * ph2[c0 + 0]); o[1] = f2b(a0.y * ph2[c0 + 1]);
      o[2] = f2b(a0.z * ph2[c0 + 2]); o[3] = f2b(a0.w * ph2[c0 + 3]);
      o[4] = f2b(a1.x * ph2[c0 + 4]); o[5] = f2b(a1.y * ph2[c0 + 5]);
      o[6] = f2b(a1.z * ph2[c0 + 6]); o[7] = f2b(a1.w * ph2[c0 + 7]);
      Qf[s][ks] = o;
    }
  }

  // S^T = K' Q'^T : acc[s][jt] lane holds S[q = i0w+s*16+fr][j = jt*16+fq*4+rr]
  f32x4 acc[2][16] = {};
#pragma unroll
  for (int ks = 0; ks < 5; ++ks) {
#pragma unroll
    for (int jt = 0; jt < 16; ++jt) {
      const int row = jt * 16 + fr;
      const short8v a = *(const short8v*)(Ks + row * 384 + (((ks * 4 + fq) ^ (row & 7)) << 4));
      acc[0][jt] = __builtin_amdgcn_mfma_f32_16x16x32_bf16(a, Qf[0][ks], acc[0][jt], 0, 0, 0);
      acc[1][jt] = __builtin_amdgcn_mfma_f32_16x16x32_bf16(a, Qf[1][ks], acc[1][jt], 0, 0, 0);
    }
  }

  // softmax: row q is lane-local over 64 vals + reduce across the 4 fq lanes
  float rsv0, rsv1;
#pragma unroll
  for (int s = 0; s < 2; ++s) {
    float m = -1e30f;
#pragma unroll
    for (int jt = 0; jt < 16; ++jt)
#pragma unroll
      for (int rr = 0; rr < 4; ++rr) m = fmaxf(m, acc[s][jt][rr]);
    m = fmaxf(m, __shfl_xor(m, 16));
    m = fmaxf(m, __shfl_xor(m, 32));
    float sm = 0.f;
#pragma unroll
    for (int jt = 0; jt < 16; ++jt)
#pragma unroll
      for (int rr = 0; rr < 4; ++rr) {
        const float e = __expf(acc[s][jt][rr] - m);
        acc[s][jt][rr] = e;
        sm += e;
      }
    sm += __shfl_xor(sm, 16);
    sm += __shfl_xor(sm, 32);
    const float r = 1.0f / sm;
    if (s == 0) rsv0 = r; else rsv1 = r;
  }
  if (fq == 0) rs_l[w * 32 + fr] = rsv0;
  if (fq == 1) rs_l[w * 32 + 16 + fr] = rsv1;

  // PV: per 32-j step, round-trip P through per-wave LDS into A-frag layout
  f32x4 oac[2][2] = {};
  char* pw = Pw + w * 2560;
#pragma unroll
  for (int ks = 0; ks < 8; ++ks) {
#pragma unroll
    for (int s = 0; s < 2; ++s) {
#pragma unroll
      for (int j2 = 0; j2 < 2; ++j2) {
        const int jt = ks * 2 + j2;
        short4 pk;
        pk.x = f2b(acc[s][jt][0]); pk.y = f2b(acc[s][jt][1]);
        pk.z = f2b(acc[s][jt][2]); pk.w = f2b(acc[s][jt][3]);
        *(short4*)(pw + (s * 16 + fr) * 80 + j2 * 32 + fq * 8) = pk;
      }
    }
    asm volatile("s_waitcnt lgkmcnt(0)" ::: "memory");
    __builtin_amdgcn_sched_barrier(0);
    const short8v pa0 = *(const short8v*)(pw + fr * 80 + fq * 16);
    const short8v pa1 = *(const short8v*)(pw + (16 + fr) * 80 + fq * 16);
    const int sw = (((ks * 4 + fq) ^ (fr & 7)) << 4);
    const short8v vb0 = *(const short8v*)(Vt + fr * 512 + sw);
    const short8v vb1 = *(const short8v*)(Vt + (16 + fr) * 512 + sw);
    oac[0][0] = __builtin_amdgcn_mfma_f32_16x16x32_bf16(pa0, vb0, oac[0][0], 0, 0, 0);
    oac[0][1] = __builtin_amdgcn_mfma_f32_16x16x32_bf16(pa0, vb1, oac[0][1], 0, 0, 0);
    oac[1][0] = __builtin_amdgcn_mfma_f32_16x16x32_bf16(pa1, vb0, oac[1][0], 0, 0, 0);
    oac[1][1] = __builtin_amdgcn_mfma_f32_16x16x32_bf16(pa1, vb1, oac[1][1], 0, 0, 0);
    asm volatile("s_waitcnt lgkmcnt(0)" ::: "memory");
    __builtin_amdgcn_sched_barrier(0);
  }

  // epilogue: O[q][d] = oac[s][nt], row = fq*4+rr, col = fr
#pragma unroll
  for (int s = 0; s < 2; ++s) {
#pragma unroll
    for (int rr = 0; rr < 4; ++rr) {
      const float rs = rs_l[w * 32 + s * 16 + fq * 4 + rr];
      const int node = bnode + i0w + s * 16 + fq * 4 + rr;
#pragma unroll
      for (int nt = 0; nt < 2; ++nt)
        obf[(size_t)node * 256 + hh * 32 + nt * 16 + fr] = f2b(oac[s][nt][rr] * rs);
    }
  }
}

// ---------------------------------------------------------------- residual + BN stats
__global__ __launch_bounds__(256) void k_resbn_stats(const float* __restrict__ op,
                                                     float* __restrict__ h,
                                                     float* __restrict__ accum) {
  const int col = threadIdx.x;
  const int r0 = blockIdx.x * 32;
  float s = 0.f, ss = 0.f;
#pragma unroll 8
  for (int r = 0; r < 32; ++r) {
    const int idx = (r0 + r) * DD + col;
    const float v = op[idx] + h[idx];
    h[idx] = v;
    s += v;
    ss += v * v;
  }
  atomicAdd(&accum[col], s);
  atomicAdd(&accum[DD + col], ss);
}

// ---------------------------------------------------------------- BN apply (+ bf16 copy)
__global__ __launch_bounds__(256) void k_bn_apply(const float* __restrict__ h,
                                                  const float* __restrict__ accum,
                                                  const float* __restrict__ gamma,
                                                  const float* __restrict__ beta,
                                                  float* __restrict__ outp,
                                                  short* __restrict__ hbf, int l) {
  const int idx = blockIdx.x * 256 + threadIdx.x;
  const int col = idx & 255;
  const float mean = accum[col] * (1.0f / NT);
  const float var = accum[DD + col] * (1.0f / NT) - mean * mean;
  const float rstd = rsqrtf(var + 1e-5f);
  const float v = (h[idx] - mean) * rstd * gamma[l * DD + col] + beta[l * DD + col];
  outp[idx] = v;
  hbf[idx] = f2b(v);
}

// ================================================================ host
extern "C" void kernel_launch(void* const* d_in, const int* in_sizes, int n_in,
                              void* d_out, int out_size, void* d_ws, size_t ws_size,
                              hipStream_t stream) {
  (void)in_sizes; (void)n_in; (void)out_size; (void)ws_size;
  const float* x    = (const float*)d_in[0];
  const float* z    = (const float*)d_in[1];
  const float* Lam  = (const float*)d_in[2];
  const float* Wq   = (const float*)d_in[4];
  const float* Wk   = (const float*)d_in[5];
  const float* Wv   = (const float*)d_in[6];
  const float* Wo   = (const float*)d_in[7];
  const float* bq   = (const float*)d_in[8];
  const float* bk   = (const float*)d_in[9];
  const float* bv   = (const float*)d_in[10];
  const float* bo   = (const float*)d_in[11];
  const float* pW1  = (const float*)d_in[12];
  const float* pb1  = (const float*)d_in[13];
  const float* pW2  = (const float*)d_in[14];
  const float* pb2  = (const float*)d_in[15];
  const float* gam  = (const float*)d_in[16];
  const float* bet  = (const float*)d_in[17];
  float* out = (float*)d_out;

  float* h    = (float*)d_ws;              // 8 MB fp32 running h
  float* op   = h + HD2;                   // 8 MB fp32 o-projection out
  short* hbf  = (short*)(op + HD2);        // 4 MB bf16 h
  short* qbf  = hbf + HD2;                 // 4 MB
  short* kbf  = qbf + HD2;
  short* vbf  = kbf + HD2;
  short* obf  = vbf + HD2;                 // attn out bf16
  short* Wt   = obf + HD2;                 // 2 MB (16 mats x 256x256 bf16)
  float* phi  = (float*)(Wt + 16 * DD * DD);
  float* bna  = phi + NB * NH * QP;

  k_init<<<2048, 256, 0, stream>>>(x, z, h, hbf, out + HD2);
  k_wt<<<dim3(16, 8), 256, 0, stream>>>(Wq, Wk, Wv, Wo, Wt);
  for (int l = 0; l < 4; ++l) {
    k_phi<<<8, 256, 0, stream>>>(Lam, pW1, pb1, pW2, pb2, phi, l);
    k_proj<<<dim3(64, 2, 3), 256, 0, stream>>>(hbf, Wt + (size_t)l * 4 * DD * DD,
                                               bq + l * DD, bk + l * DD, bv + l * DD,
                                               qbf, kbf, vbf, nullptr, 0, QSCALE);
    k_attn2<<<256, 512, 0, stream>>>(qbf, kbf, vbf, z, phi, obf);
    k_proj<<<dim3(64, 2, 1), 256, 0, stream>>>(obf, Wt + (size_t)l * 4 * DD * DD,
                                               bo + l * DD, bo + l * DD, bo + l * DD,
                                               nullptr, nullptr, nullptr, op, 3, 1.0f);
    hipMemsetAsync(bna, 0, 2 * DD * sizeof(float), stream);
    k_resbn_stats<<<256, 256, 0, stream>>>(op, h, bna);
    k_bn_apply<<<8192, 256, 0, stream>>>(h, bna, gam, bet, (l == 3 ? out : h), hbf, l);
  }
}

// Round 4
// 198.023 us; speedup vs baseline: 5.7958x; 1.3953x over previous
//
#include <hip/hip_runtime.h>
#include <hip/hip_bf16.h>

typedef __hip_bfloat16 bf16;
typedef __attribute__((ext_vector_type(8))) short short8v;   // 8 bf16 (4 VGPRs)
typedef __attribute__((ext_vector_type(4))) float f32x4;

constexpr int NB  = 32;
constexpr int NM  = 256;
constexpr int DD  = 256;
constexpr int NH  = 8;
constexpr int QP  = 64;
constexpr int FF  = 32;
constexpr int NT  = NB * NM;        // 8192
constexpr int HD2 = NT * DD;        // 2097152
constexpr float QSCALE = 0.17677669529663687f;

__device__ __forceinline__ short f2b(float f) {
  union { bf16 h; short s; } u;
  u.h = __float2bfloat16(f);
  return u.s;
}

// ---------------------------------------------------------------- init: h=x (f32+bf16), out_z=z, zero bna
__global__ __launch_bounds__(256) void k_init(const float* __restrict__ x,
                                              const float* __restrict__ z,
                                              float* __restrict__ h,
                                              short* __restrict__ hbf,
                                              float* __restrict__ outz,
                                              float* __restrict__ bna) {
  int idx = blockIdx.x * 256 + threadIdx.x;               // 524288 float4s
  float4 v = ((const float4*)x)[idx];
  ((float4*)h)[idx] = v;
  short4 s;
  s.x = f2b(v.x); s.y = f2b(v.y); s.z = f2b(v.z); s.w = f2b(v.w);
  ((short4*)hbf)[idx] = s;
  if (idx < (NT * QP * 2) / 4)
    ((float4*)outz)[idx] = ((const float4*)z)[idx];
  if (idx < 4 * 512) bna[idx] = 0.f;                      // 4 layers x (sum,ssum)[256]
}

// ---------------------------------------------------------------- W^T precompute (bf16)
__global__ __launch_bounds__(256) void k_wt(const float* __restrict__ Wq,
                                            const float* __restrict__ Wk,
                                            const float* __restrict__ Wv,
                                            const float* __restrict__ Wo,
                                            short* __restrict__ Wt) {
  __shared__ float Ts[32][33];
  const int mat = blockIdx.x;
  const int l = mat >> 2, wsel = mat & 3;
  const float* W = (wsel == 0 ? Wq : wsel == 1 ? Wk : wsel == 2 ? Wv : Wo) + l * DD * DD;
  const int j0 = blockIdx.y * 32;
  short* out = Wt + (size_t)mat * DD * DD;
  const int t = threadIdx.x;
  const int jj = t & 31, kk8 = t >> 5;
  for (int k0 = 0; k0 < DD; k0 += 32) {
    __syncthreads();
#pragma unroll
    for (int s = 0; s < 4; ++s) {
      const int kl = s * 8 + kk8;
      Ts[kl][jj] = W[(k0 + kl) * DD + j0 + jj];
    }
    __syncthreads();
#pragma unroll
    for (int s = 0; s < 4; ++s) {
      const int jl = (t >> 5) + s * 8;
      const int kl = t & 31;
      out[(size_t)(j0 + jl) * DD + k0 + kl] = f2b(Ts[kl][jl]);
    }
  }
}

// ---------------------------------------------------------------- MFMA qkv projection GEMM
// grid (64, 2, 3): 128x128 tiles, z = {q,k,v}
__global__ __launch_bounds__(256) void k_proj(const short* __restrict__ Abf,
                                              const short* __restrict__ WtL,
                                              const float* __restrict__ b0,
                                              const float* __restrict__ b1,
                                              const float* __restrict__ b2,
                                              short* __restrict__ o0,
                                              short* __restrict__ o1,
                                              short* __restrict__ o2) {
  __shared__ __align__(16) short As[128 * 128];
  __shared__ __align__(16) short Bs[128 * 128];
  const int t = threadIdx.x;
  const int m0 = blockIdx.x * 128;
  const int j0 = blockIdx.y * 128;
  const int zz = blockIdx.z;
  const short* W = WtL + (size_t)zz * DD * DD;
  const float* bb = zz == 0 ? b0 : zz == 1 ? b1 : b2;
  short* obf = zz == 0 ? o0 : zz == 1 ? o1 : o2;
  const float scale = (zz == 0) ? QSCALE : 1.0f;

  const int lane = t & 63, w = t >> 6;
  const int wr = w >> 1, wc = w & 1;
  const int fr = lane & 15, fq = lane >> 4;

  f32x4 acc[4][4] = {};

  for (int kb = 0; kb < 2; ++kb) {
    __syncthreads();
#pragma unroll
    for (int p = 0; p < 8; ++p) {
      const int c = p * 256 + t;
      const int r = c >> 4, ch = c & 15;
      const int sw = ((ch ^ (r & 7)) << 4);
      *(short8v*)((char*)As + r * 256 + sw) =
          *(const short8v*)(Abf + (size_t)(m0 + r) * 256 + kb * 128 + ch * 8);
      *(short8v*)((char*)Bs + r * 256 + sw) =
          *(const short8v*)(W + (size_t)(j0 + r) * 256 + kb * 128 + ch * 8);
    }
    __syncthreads();
#pragma unroll
    for (int ks = 0; ks < 4; ++ks) {
      short8v a[4], bfrag[4];
#pragma unroll
      for (int m = 0; m < 4; ++m) {
        const int rA = wr * 64 + m * 16 + fr;
        a[m] = *(const short8v*)((const char*)As + rA * 256 + (((ks * 4 + fq) ^ (rA & 7)) << 4));
        const int rB = wc * 64 + m * 16 + fr;
        bfrag[m] = *(const short8v*)((const char*)Bs + rB * 256 + (((ks * 4 + fq) ^ (rB & 7)) << 4));
      }
#pragma unroll
      for (int m = 0; m < 4; ++m)
#pragma unroll
        for (int n = 0; n < 4; ++n)
          acc[m][n] = __builtin_amdgcn_mfma_f32_16x16x32_bf16(a[m], bfrag[n], acc[m][n], 0, 0, 0);
    }
  }
#pragma unroll
  for (int n = 0; n < 4; ++n) {
    const int col = j0 + wc * 64 + n * 16 + fr;
    const float bv = bb[col];
#pragma unroll
    for (int m = 0; m < 4; ++m) {
#pragma unroll
      for (int rr = 0; rr < 4; ++rr) {
        const int row = m0 + wr * 64 + m * 16 + fq * 4 + rr;
        obf[(size_t)row * 256 + col] = f2b((acc[m][n][rr] + bv) * scale);
      }
    }
  }
}

// ---------------------------------------------------------------- fused O-proj + residual + BN stats
// grid (128, 2): 64x128 tiles. h <- h + A@Wo + bo; atomicAdd col sums to bna.
__global__ __launch_bounds__(256) void k_projo(const short* __restrict__ Abf,
                                               const short* __restrict__ WtO,
                                               const float* __restrict__ bo,
                                               float* __restrict__ h,
                                               float* __restrict__ bna) {
  __shared__ __align__(16) short As[64 * 128];
  __shared__ __align__(16) short Bs[128 * 128];
  __shared__ float sred[2][128][2];
  const int t = threadIdx.x;
  const int m0 = blockIdx.x * 64;
  const int c0 = blockIdx.y * 128;
  const int lane = t & 63, w = t >> 6;
  const int wr = w >> 1, wc = w & 1;
  const int fr = lane & 15, fq = lane >> 4;

  f32x4 acc[2][4] = {};
  for (int kb = 0; kb < 2; ++kb) {
    __syncthreads();
#pragma unroll
    for (int p = 0; p < 4; ++p) {
      const int c = p * 256 + t;
      const int r = c >> 4, ch = c & 15;
      const int sw = ((ch ^ (r & 7)) << 4);
      *(short8v*)((char*)As + r * 256 + sw) =
          *(const short8v*)(Abf + (size_t)(m0 + r) * 256 + kb * 128 + ch * 8);
    }
#pragma unroll
    for (int p = 0; p < 8; ++p) {
      const int c = p * 256 + t;
      const int r = c >> 4, ch = c & 15;
      const int sw = ((ch ^ (r & 7)) << 4);
      *(short8v*)((char*)Bs + r * 256 + sw) =
          *(const short8v*)(WtO + (size_t)(c0 + r) * 256 + kb * 128 + ch * 8);
    }
    __syncthreads();
#pragma unroll
    for (int ks = 0; ks < 4; ++ks) {
      short8v a[2], bfrag[4];
#pragma unroll
      for (int m = 0; m < 2; ++m) {
        const int rA = wr * 32 + m * 16 + fr;
        a[m] = *(const short8v*)((const char*)As + rA * 256 + (((ks * 4 + fq) ^ (rA & 7)) << 4));
      }
#pragma unroll
      for (int n = 0; n < 4; ++n) {
        const int rB = wc * 64 + n * 16 + fr;
        bfrag[n] = *(const short8v*)((const char*)Bs + rB * 256 + (((ks * 4 + fq) ^ (rB & 7)) << 4));
      }
#pragma unroll
      for (int m = 0; m < 2; ++m)
#pragma unroll
        for (int n = 0; n < 4; ++n)
          acc[m][n] = __builtin_amdgcn_mfma_f32_16x16x32_bf16(a[m], bfrag[n], acc[m][n], 0, 0, 0);
    }
  }
  // epilogue: residual add, h write, column stats
#pragma unroll
  for (int n = 0; n < 4; ++n) {
    const int col = c0 + wc * 64 + n * 16 + fr;
    const float bv = bo[col];
    float s = 0.f, ss = 0.f;
#pragma unroll
    for (int m = 0; m < 2; ++m) {
#pragma unroll
      for (int rr = 0; rr < 4; ++rr) {
        const int row = m0 + wr * 32 + m * 16 + fq * 4 + rr;
        const size_t idx = (size_t)row * 256 + col;
        const float v = acc[m][n][rr] + bv + h[idx];
        h[idx] = v;
        s += v;
        ss += v * v;
      }
    }
    // reduce over the 4 fq lanes (xor 16, 32)
    s += __shfl_xor(s, 16); s += __shfl_xor(s, 32);
    ss += __shfl_xor(ss, 16); ss += __shfl_xor(ss, 32);
    if (fq == 0) {
      sred[wr][wc * 64 + n * 16 + fr][0] = s;
      sred[wr][wc * 64 + n * 16 + fr][1] = ss;
    }
  }
  __syncthreads();
  if (t < 128) {
    const float s = sred[0][t][0] + sred[1][t][0];
    const float ss = sred[0][t][1] + sred[1][t][1];
    atomicAdd(&bna[c0 + t], s);
    atomicAdd(&bna[256 + c0 + t], ss);
  }
}

// ---------------------------------------------------------------- fused phi + bias + attention, MFMA
// One block per (b,h), 512 threads = 8 waves, each wave owns 32 q-rows.
// Augmented GEMM: S = Q'K'^T with Q'=[q*scale, phi.z], K'=[k, z], Kdim=160.
__global__ __launch_bounds__(512, 2) void k_attn2(const short* __restrict__ qbf,
                                                  const short* __restrict__ kbf,
                                                  const short* __restrict__ vbf,
                                                  const float* __restrict__ z,
                                                  const float* __restrict__ Lam,
                                                  const float* __restrict__ pW1,
                                                  const float* __restrict__ pb1,
                                                  const float* __restrict__ pW2,
                                                  const float* __restrict__ pb2,
                                                  short* __restrict__ obf, int l) {
  __shared__ __align__(16) char Ks[256 * 384];     // K'[256][192 bf16], XOR-swz 16B chunks
  __shared__ __align__(16) char Vt[32 * 512];      // V^T[32][256 bf16], XOR-swz
  __shared__ __align__(16) char Pw[8 * 2 * 2560];  // per-wave double-buffered P tile
  __shared__ float rs_l[8 * 32];
  __shared__ float ph2[128];
  const int t = threadIdx.x;
  const int bh = blockIdx.x;
  const int b = bh >> 3, hh = bh & 7;
  const int bnode = b * 256;

  // phi MLP for this (b,h): 64 qp values
  if (t < 64) {
    const float lam = Lam[b * QP + t];
    const float* w1 = pW1 + l * FF;
    const float* bb1 = pb1 + l * FF;
    const float* w2 = pW2 + l * FF * NH;
    float a = pb2[l * NH + hh];
#pragma unroll
    for (int f = 0; f < FF; ++f) {
      float u = lam * w1[f] + bb1[f];
      u = u > 0.f ? u : 0.f;
      a += u * w2[f * NH + hh];
    }
    ph2[2 * t] = a;
    ph2[2 * t + 1] = a;
  }
  {
    const int r = t >> 1, half = t & 1;
    const size_t rowbase = (size_t)(bnode + r) * 256 + hh * 32;
    // K' cols 0..31 = k slice (bf16 direct)
#pragma unroll
    for (int j2 = 0; j2 < 2; ++j2) {
      const int c = half * 2 + j2;
      short8v v = *(const short8v*)(kbf + rowbase + c * 8);
      *(short8v*)(Ks + r * 384 + ((c ^ (r & 7)) << 4)) = v;
    }
    // K' cols 32..159 = z row (fp32 -> bf16)
    const float* zrow = z + (size_t)(bnode + r) * 128 + half * 64;
#pragma unroll
    for (int cc = 0; cc < 8; ++cc) {
      const float4 a0 = *(const float4*)(zrow + cc * 8);
      const float4 a1 = *(const float4*)(zrow + cc * 8 + 4);
      short8v o;
      o[0] = f2b(a0.x); o[1] = f2b(a0.y); o[2] = f2b(a0.z); o[3] = f2b(a0.w);
      o[4] = f2b(a1.x); o[5] = f2b(a1.y); o[6] = f2b(a1.z); o[7] = f2b(a1.w);
      const int c = 4 + half * 8 + cc;
      *(short8v*)(Ks + r * 384 + ((c ^ (r & 7)) << 4)) = o;
    }
    // V^T staging (scalar transpose)
    const short* vrow = vbf + rowbase + half * 16;
    short8v v0 = *(const short8v*)(vrow);
    short8v v1 = *(const short8v*)(vrow + 8);
#pragma unroll
    for (int dd = 0; dd < 16; ++dd) {
      const int d = half * 16 + dd;
      const short val = dd < 8 ? v0[dd] : v1[dd - 8];
      *(short*)(Vt + d * 512 + (((r >> 3) ^ (d & 7)) << 4) + (r & 7) * 2) = val;
    }
  }
  __syncthreads();

  const int lane = t & 63, w = t >> 6;
  const int fr = lane & 15, fq = lane >> 4;
  const int i0w = w * 32;

  // Q' fragments in registers: Qf[s][ks]
  short8v Qf[2][5];
#pragma unroll
  for (int s = 0; s < 2; ++s) {
    const int node = bnode + i0w + s * 16 + fr;
    Qf[s][0] = *(const short8v*)(qbf + (size_t)node * 256 + hh * 32 + fq * 8);
    const float* zr = z + (size_t)node * 128;
#pragma unroll
    for (int ks = 1; ks < 5; ++ks) {
      const int c0 = (ks - 1) * 32 + fq * 8;
      const float4 a0 = *(const float4*)(zr + c0);
      const float4 a1 = *(const float4*)(zr + c0 + 4);
      short8v o;
      o[0] = f2b(a0.x * ph2[c0 + 0]); o[1] = f2b(a0.y * ph2[c0 + 1]);
      o[2] = f2b(a0.z * ph2[c0 + 2]); o[3] = f2b(a0.w * ph2[c0 + 3]);
      o[4] = f2b(a1.x * ph2[c0 + 4]); o[5] = f2b(a1.y * ph2[c0 + 5]);
      o[6] = f2b(a1.z * ph2[c0 + 6]); o[7] = f2b(a1.w * ph2[c0 + 7]);
      Qf[s][ks] = o;
    }
  }

  // S^T = K' Q'^T : acc[s][jt] lane holds S[q = i0w+s*16+fr][j = jt*16+fq*4+rr]
  f32x4 acc[2][16] = {};
#pragma unroll
  for (int ks = 0; ks < 5; ++ks) {
#pragma unroll
    for (int jt = 0; jt < 16; ++jt) {
      const int row = jt * 16 + fr;
      const short8v a = *(const short8v*)(Ks + row * 384 + (((ks * 4 + fq) ^ (row & 7)) << 4));
      acc[0][jt] = __builtin_amdgcn_mfma_f32_16x16x32_bf16(a, Qf[0][ks], acc[0][jt], 0, 0, 0);
      acc[1][jt] = __builtin_amdgcn_mfma_f32_16x16x32_bf16(a, Qf[1][ks], acc[1][jt], 0, 0, 0);
    }
  }

  // softmax: row q is lane-local + reduce across fq lanes
  float rsv0, rsv1;
#pragma unroll
  for (int s = 0; s < 2; ++s) {
    float m = -1e30f;
#pragma unroll
    for (int jt = 0; jt < 16; ++jt)
#pragma unroll
      for (int rr = 0; rr < 4; ++rr) m = fmaxf(m, acc[s][jt][rr]);
    m = fmaxf(m, __shfl_xor(m, 16));
    m = fmaxf(m, __shfl_xor(m, 32));
    float sm = 0.f;
#pragma unroll
    for (int jt = 0; jt < 16; ++jt)
#pragma unroll
      for (int rr = 0; rr < 4; ++rr) {
        const float e = __expf(acc[s][jt][rr] - m);
        acc[s][jt][rr] = e;
        sm += e;
      }
    sm += __shfl_xor(sm, 16);
    sm += __shfl_xor(sm, 32);
    const float r = 1.0f / sm;
    if (s == 0) rsv0 = r; else rsv1 = r;
  }
  if (fq == 0) rs_l[w * 32 + fr] = rsv0;
  if (fq == 1) rs_l[w * 32 + 16 + fr] = rsv1;

  // PV: per 32-j step, round-trip P through double-buffered per-wave LDS
  f32x4 oac[2][2] = {};
  char* pw0 = Pw + w * 5120;
#pragma unroll
  for (int ks = 0; ks < 8; ++ks) {
    char* pw = pw0 + (ks & 1) * 2560;
#pragma unroll
    for (int s = 0; s < 2; ++s) {
#pragma unroll
      for (int j2 = 0; j2 < 2; ++j2) {
        const int jt = ks * 2 + j2;
        short4 pk;
        pk.x = f2b(acc[s][jt][0]); pk.y = f2b(acc[s][jt][1]);
        pk.z = f2b(acc[s][jt][2]); pk.w = f2b(acc[s][jt][3]);
        *(short4*)(pw + (s * 16 + fr) * 80 + j2 * 32 + fq * 8) = pk;
      }
    }
    asm volatile("s_waitcnt lgkmcnt(0)" ::: "memory");
    __builtin_amdgcn_sched_barrier(0);
    const short8v pa0 = *(const short8v*)(pw + fr * 80 + fq * 16);
    const short8v pa1 = *(const short8v*)(pw + (16 + fr) * 80 + fq * 16);
    const int sw = (((ks * 4 + fq) ^ (fr & 7)) << 4);
    const short8v vb0 = *(const short8v*)(Vt + fr * 512 + sw);
    const short8v vb1 = *(const short8v*)(Vt + (16 + fr) * 512 + sw);
    oac[0][0] = __builtin_amdgcn_mfma_f32_16x16x32_bf16(pa0, vb0, oac[0][0], 0, 0, 0);
    oac[0][1] = __builtin_amdgcn_mfma_f32_16x16x32_bf16(pa0, vb1, oac[0][1], 0, 0, 0);
    oac[1][0] = __builtin_amdgcn_mfma_f32_16x16x32_bf16(pa1, vb0, oac[1][0], 0, 0, 0);
    oac[1][1] = __builtin_amdgcn_mfma_f32_16x16x32_bf16(pa1, vb1, oac[1][1], 0, 0, 0);
  }

  // epilogue
#pragma unroll
  for (int s = 0; s < 2; ++s) {
#pragma unroll
    for (int rr = 0; rr < 4; ++rr) {
      const float rs = rs_l[w * 32 + s * 16 + fq * 4 + rr];
      const int node = bnode + i0w + s * 16 + fq * 4 + rr;
#pragma unroll
      for (int nt = 0; nt < 2; ++nt)
        obf[(size_t)node * 256 + hh * 32 + nt * 16 + fr] = f2b(oac[s][nt][rr] * rs);
    }
  }
}

// ---------------------------------------------------------------- BN apply (+ bf16 copy)
__global__ __launch_bounds__(256) void k_bn_apply(const float* __restrict__ h,
                                                  const float* __restrict__ accum,
                                                  const float* __restrict__ gamma,
                                                  const float* __restrict__ beta,
                                                  float* __restrict__ outp,
                                                  short* __restrict__ hbf, int l) {
  const int idx = blockIdx.x * 256 + threadIdx.x;
  const int col = idx & 255;
  const float mean = accum[col] * (1.0f / NT);
  const float var = accum[DD + col] * (1.0f / NT) - mean * mean;
  const float rstd = rsqrtf(var + 1e-5f);
  const float v = (h[idx] - mean) * rstd * gamma[l * DD + col] + beta[l * DD + col];
  outp[idx] = v;
  hbf[idx] = f2b(v);
}

// ================================================================ host
extern "C" void kernel_launch(void* const* d_in, const int* in_sizes, int n_in,
                              void* d_out, int out_size, void* d_ws, size_t ws_size,
                              hipStream_t stream) {
  (void)in_sizes; (void)n_in; (void)out_size; (void)ws_size;
  const float* x    = (const float*)d_in[0];
  const float* z    = (const float*)d_in[1];
  const float* Lam  = (const float*)d_in[2];
  const float* Wq   = (const float*)d_in[4];
  const float* Wk   = (const float*)d_in[5];
  const float* Wv   = (const float*)d_in[6];
  const float* Wo   = (const float*)d_in[7];
  const float* bq   = (const float*)d_in[8];
  const float* bk   = (const float*)d_in[9];
  const float* bv   = (const float*)d_in[10];
  const float* bo   = (const float*)d_in[11];
  const float* pW1  = (const float*)d_in[12];
  const float* pb1  = (const float*)d_in[13];
  const float* pW2  = (const float*)d_in[14];
  const float* pb2  = (const float*)d_in[15];
  const float* gam  = (const float*)d_in[16];
  const float* bet  = (const float*)d_in[17];
  float* out = (float*)d_out;

  float* h    = (float*)d_ws;              // 8 MB fp32 running h
  short* hbf  = (short*)(h + HD2);         // 4 MB bf16 h
  short* qbf  = hbf + HD2;                 // 4 MB
  short* kbf  = qbf + HD2;
  short* vbf  = kbf + HD2;
  short* obf  = vbf + HD2;                 // attn out bf16
  short* Wt   = obf + HD2;                 // 2 MB (16 mats x 256x256 bf16)
  float* bna  = (float*)(Wt + 16 * DD * DD);  // 4 layers x 512

  k_init<<<2048, 256, 0, stream>>>(x, z, h, hbf, out + HD2, bna);
  k_wt<<<dim3(16, 8), 256, 0, stream>>>(Wq, Wk, Wv, Wo, Wt);
  for (int l = 0; l < 4; ++l) {
    float* bnal = bna + l * 512;
    k_proj<<<dim3(64, 2, 3), 256, 0, stream>>>(hbf, Wt + (size_t)l * 4 * DD * DD,
                                               bq + l * DD, bk + l * DD, bv + l * DD,
                                               qbf, kbf, vbf);
    k_attn2<<<256, 512, 0, stream>>>(qbf, kbf, vbf, z, Lam, pW1, pb1, pW2, pb2, obf, l);
    k_projo<<<dim3(128, 2), 256, 0, stream>>>(obf, Wt + (size_t)(l * 4 + 3) * DD * DD,
                                              bo + l * DD, h, bnal);
    k_bn_apply<<<8192, 256, 0, stream>>>(h, bnal, gam, bet, (l == 3 ? out : h), hbf, l);
  }
}

// Round 5
// 169.414 us; speedup vs baseline: 6.7745x; 1.1689x over previous
//
#include <hip/hip_runtime.h>
#include <hip/hip_bf16.h>

typedef __hip_bfloat16 bf16;
typedef __attribute__((ext_vector_type(8))) short short8v;   // 8 bf16 (4 VGPRs)
typedef __attribute__((ext_vector_type(4))) float f32x4;

constexpr int NB  = 32;
constexpr int NM  = 256;
constexpr int DD  = 256;
constexpr int NH  = 8;
constexpr int QP  = 64;
constexpr int FF  = 32;
constexpr int NT  = NB * NM;        // 8192
constexpr int HD2 = NT * DD;        // 2097152
constexpr float QSCALE = 0.17677669529663687f;

__device__ __forceinline__ float b2f(unsigned short u) {
  return __uint_as_float(((unsigned)u) << 16);
}
__device__ __forceinline__ short f2b(float f) {
  union { bf16 h; short s; } u;
  u.h = __float2bfloat16(f);
  return u.s;
}

// ---------------------------------------------------------------- init: out_z=z, zbf=bf16(z), bna=0
__global__ __launch_bounds__(256) void k_init(const float* __restrict__ z,
                                              float* __restrict__ outz,
                                              short* __restrict__ zbf,
                                              float* __restrict__ bna) {
  const int idx = blockIdx.x * 256 + threadIdx.x;     // 262144 = NT*128/4
  const float4 v = ((const float4*)z)[idx];
  ((float4*)outz)[idx] = v;
  short4 s;
  s.x = f2b(v.x); s.y = f2b(v.y); s.z = f2b(v.z); s.w = f2b(v.w);
  ((short4*)zbf)[idx] = s;
  if (idx < 4 * 512) bna[idx] = 0.f;                  // 4 layers x (sum,ssum)[256]
}

// ---------------------------------------------------------------- W^T precompute (bf16)
__global__ __launch_bounds__(256) void k_wt(const float* __restrict__ Wq,
                                            const float* __restrict__ Wk,
                                            const float* __restrict__ Wv,
                                            const float* __restrict__ Wo,
                                            short* __restrict__ Wt) {
  __shared__ float Ts[32][33];
  const int mat = blockIdx.x;
  const int l = mat >> 2, wsel = mat & 3;
  const float* W = (wsel == 0 ? Wq : wsel == 1 ? Wk : wsel == 2 ? Wv : Wo) + l * DD * DD;
  const int j0 = blockIdx.y * 32;
  short* out = Wt + (size_t)mat * DD * DD;
  const int t = threadIdx.x;
  const int jj = t & 31, kk8 = t >> 5;
  for (int k0 = 0; k0 < DD; k0 += 32) {
    __syncthreads();
#pragma unroll
    for (int s = 0; s < 4; ++s) {
      const int kl = s * 8 + kk8;
      Ts[kl][jj] = W[(k0 + kl) * DD + j0 + jj];
    }
    __syncthreads();
#pragma unroll
    for (int s = 0; s < 4; ++s) {
      const int jl = (t >> 5) + s * 8;
      const int kl = t & 31;
      out[(size_t)(j0 + jl) * DD + k0 + kl] = f2b(Ts[kl][jl]);
    }
  }
}

// ---------------------------------------------------------------- phi for ALL layers: [L][B][H][QP]
__global__ __launch_bounds__(256) void k_phi_all(const float* __restrict__ Lam,
                                                 const float* __restrict__ W1,
                                                 const float* __restrict__ b1,
                                                 const float* __restrict__ W2,
                                                 const float* __restrict__ b2,
                                                 float* __restrict__ phiAll) {
  const int l = blockIdx.y;
  const int t = blockIdx.x * 256 + threadIdx.x;       // B*QP = 2048
  const int b = t >> 6, qp = t & 63;
  const float lam = Lam[b * QP + qp];
  const float* w1 = W1 + l * FF;
  const float* bb1 = b1 + l * FF;
  const float* w2 = W2 + l * FF * NH;
  const float* bb2 = b2 + l * NH;
  float acc[NH];
#pragma unroll
  for (int h = 0; h < NH; ++h) acc[h] = bb2[h];
  for (int f = 0; f < FF; ++f) {
    float a = lam * w1[f] + bb1[f];
    a = a > 0.f ? a : 0.f;
#pragma unroll
    for (int h = 0; h < NH; ++h) acc[h] += a * w2[f * NH + h];
  }
#pragma unroll
  for (int h = 0; h < NH; ++h)
    phiAll[(((size_t)l * NB + b) * NH + h) * QP + qp] = acc[h];
}

// ---------------------------------------------------------------- MFMA qkv projection GEMM (BN on load)
// grid (64, 2, 3): 128x128 tiles, z = {q,k,v}. A = BN(hsrc) in bf16.
__global__ __launch_bounds__(256) void k_proj(const float* __restrict__ hsrc,
                                              const short* __restrict__ WtL,
                                              const float* __restrict__ bnstat,   // null = identity
                                              const float* __restrict__ gamma,
                                              const float* __restrict__ beta,
                                              const float* __restrict__ b0,
                                              const float* __restrict__ b1,
                                              const float* __restrict__ b2,
                                              short* __restrict__ o0,
                                              short* __restrict__ o1,
                                              short* __restrict__ o2) {
  __shared__ __align__(16) short As[128 * 128];
  __shared__ __align__(16) short Bs[128 * 128];
  __shared__ float bnsc[256], bnsh[256];
  const int t = threadIdx.x;
  const int m0 = blockIdx.x * 128;
  const int j0 = blockIdx.y * 128;
  const int zz = blockIdx.z;
  const short* W = WtL + (size_t)zz * DD * DD;
  const float* bb = zz == 0 ? b0 : zz == 1 ? b1 : b2;
  short* obf = zz == 0 ? o0 : zz == 1 ? o1 : o2;
  const float scale = (zz == 0) ? QSCALE : 1.0f;

  if (t < 256) {
    float sc = 1.f, sh = 0.f;
    if (bnstat) {
      const float mean = bnstat[t] * (1.0f / NT);
      const float var = bnstat[256 + t] * (1.0f / NT) - mean * mean;
      const float rstd = rsqrtf(var + 1e-5f);
      sc = rstd * gamma[t];
      sh = beta[t] - mean * sc;
    }
    bnsc[t] = sc; bnsh[t] = sh;
  }

  const int lane = t & 63, w = t >> 6;
  const int wr = w >> 1, wc = w & 1;
  const int fr = lane & 15, fq = lane >> 4;

  f32x4 acc[4][4] = {};

  for (int kb = 0; kb < 2; ++kb) {
    __syncthreads();
#pragma unroll
    for (int p = 0; p < 8; ++p) {
      const int c = p * 256 + t;
      const int r = c >> 4, ch = c & 15;
      const int sw = ((ch ^ (r & 7)) << 4);
      const int col0 = kb * 128 + ch * 8;
      const float* src = hsrc + (size_t)(m0 + r) * 256 + col0;
      const float4 v0 = *(const float4*)src;
      const float4 v1 = *(const float4*)(src + 4);
      short8v o;
      o[0] = f2b(v0.x * bnsc[col0 + 0] + bnsh[col0 + 0]);
      o[1] = f2b(v0.y * bnsc[col0 + 1] + bnsh[col0 + 1]);
      o[2] = f2b(v0.z * bnsc[col0 + 2] + bnsh[col0 + 2]);
      o[3] = f2b(v0.w * bnsc[col0 + 3] + bnsh[col0 + 3]);
      o[4] = f2b(v1.x * bnsc[col0 + 4] + bnsh[col0 + 4]);
      o[5] = f2b(v1.y * bnsc[col0 + 5] + bnsh[col0 + 5]);
      o[6] = f2b(v1.z * bnsc[col0 + 6] + bnsh[col0 + 6]);
      o[7] = f2b(v1.w * bnsc[col0 + 7] + bnsh[col0 + 7]);
      *(short8v*)((char*)As + r * 256 + sw) = o;
      *(short8v*)((char*)Bs + r * 256 + sw) =
          *(const short8v*)(W + (size_t)(j0 + r) * 256 + kb * 128 + ch * 8);
    }
    __syncthreads();
#pragma unroll
    for (int ks = 0; ks < 4; ++ks) {
      short8v a[4], bfrag[4];
#pragma unroll
      for (int m = 0; m < 4; ++m) {
        const int rA = wr * 64 + m * 16 + fr;
        a[m] = *(const short8v*)((const char*)As + rA * 256 + (((ks * 4 + fq) ^ (rA & 7)) << 4));
        const int rB = wc * 64 + m * 16 + fr;
        bfrag[m] = *(const short8v*)((const char*)Bs + rB * 256 + (((ks * 4 + fq) ^ (rB & 7)) << 4));
      }
#pragma unroll
      for (int m = 0; m < 4; ++m)
#pragma unroll
        for (int n = 0; n < 4; ++n)
          acc[m][n] = __builtin_amdgcn_mfma_f32_16x16x32_bf16(a[m], bfrag[n], acc[m][n], 0, 0, 0);
    }
  }
#pragma unroll
  for (int n = 0; n < 4; ++n) {
    const int col = j0 + wc * 64 + n * 16 + fr;
    const float bv = bb[col];
#pragma unroll
    for (int m = 0; m < 4; ++m) {
#pragma unroll
      for (int rr = 0; rr < 4; ++rr) {
        const int row = m0 + wr * 64 + m * 16 + fq * 4 + rr;
        obf[(size_t)row * 256 + col] = f2b((acc[m][n][rr] + bv) * scale);
      }
    }
  }
}

// ---------------------------------------------------------------- fused O-proj + residual(BN) + stats
// grid (128, 2): 64x128 tiles. h <- BN_prev(hin) + A@Wo + bo; atomicAdd col sums to bna.
__global__ __launch_bounds__(256) void k_projo(const short* __restrict__ Abf,
                                               const short* __restrict__ WtO,
                                               const float* __restrict__ bo,
                                               const float* __restrict__ hin,
                                               float* __restrict__ hout,
                                               const float* __restrict__ bnstat,  // null = identity
                                               const float* __restrict__ gamma,
                                               const float* __restrict__ beta,
                                               float* __restrict__ bna) {
  __shared__ __align__(16) short As[64 * 128];
  __shared__ __align__(16) short Bs[128 * 128];
  __shared__ float sred[2][128][2];
  __shared__ float bnsc[256], bnsh[256];
  const int t = threadIdx.x;
  const int m0 = blockIdx.x * 64;
  const int c0 = blockIdx.y * 128;
  const int lane = t & 63, w = t >> 6;
  const int wr = w >> 1, wc = w & 1;
  const int fr = lane & 15, fq = lane >> 4;

  if (t < 256) {
    float sc = 1.f, sh = 0.f;
    if (bnstat) {
      const float mean = bnstat[t] * (1.0f / NT);
      const float var = bnstat[256 + t] * (1.0f / NT) - mean * mean;
      const float rstd = rsqrtf(var + 1e-5f);
      sc = rstd * gamma[t];
      sh = beta[t] - mean * sc;
    }
    bnsc[t] = sc; bnsh[t] = sh;
  }

  f32x4 acc[2][4] = {};
  for (int kb = 0; kb < 2; ++kb) {
    __syncthreads();
#pragma unroll
    for (int p = 0; p < 4; ++p) {
      const int c = p * 256 + t;
      const int r = c >> 4, ch = c & 15;
      const int sw = ((ch ^ (r & 7)) << 4);
      *(short8v*)((char*)As + r * 256 + sw) =
          *(const short8v*)(Abf + (size_t)(m0 + r) * 256 + kb * 128 + ch * 8);
    }
#pragma unroll
    for (int p = 0; p < 8; ++p) {
      const int c = p * 256 + t;
      const int r = c >> 4, ch = c & 15;
      const int sw = ((ch ^ (r & 7)) << 4);
      *(short8v*)((char*)Bs + r * 256 + sw) =
          *(const short8v*)(WtO + (size_t)(c0 + r) * 256 + kb * 128 + ch * 8);
    }
    __syncthreads();
#pragma unroll
    for (int ks = 0; ks < 4; ++ks) {
      short8v a[2], bfrag[4];
#pragma unroll
      for (int m = 0; m < 2; ++m) {
        const int rA = wr * 32 + m * 16 + fr;
        a[m] = *(const short8v*)((const char*)As + rA * 256 + (((ks * 4 + fq) ^ (rA & 7)) << 4));
      }
#pragma unroll
      for (int n = 0; n < 4; ++n) {
        const int rB = wc * 64 + n * 16 + fr;
        bfrag[n] = *(const short8v*)((const char*)Bs + rB * 256 + (((ks * 4 + fq) ^ (rB & 7)) << 4));
      }
#pragma unroll
      for (int m = 0; m < 2; ++m)
#pragma unroll
        for (int n = 0; n < 4; ++n)
          acc[m][n] = __builtin_amdgcn_mfma_f32_16x16x32_bf16(a[m], bfrag[n], acc[m][n], 0, 0, 0);
    }
  }
  // epilogue: BN(prev) residual add, h write, column stats
#pragma unroll
  for (int n = 0; n < 4; ++n) {
    const int col = c0 + wc * 64 + n * 16 + fr;
    const float bv = bo[col];
    const float sc = bnsc[col], sh = bnsh[col];
    float s = 0.f, ss = 0.f;
#pragma unroll
    for (int m = 0; m < 2; ++m) {
#pragma unroll
      for (int rr = 0; rr < 4; ++rr) {
        const int row = m0 + wr * 32 + m * 16 + fq * 4 + rr;
        const size_t idx = (size_t)row * 256 + col;
        const float v = acc[m][n][rr] + bv + (hin[idx] * sc + sh);
        hout[idx] = v;
        s += v;
        ss += v * v;
      }
    }
    s += __shfl_xor(s, 16); s += __shfl_xor(s, 32);
    ss += __shfl_xor(ss, 16); ss += __shfl_xor(ss, 32);
    if (fq == 0) {
      sred[wr][wc * 64 + n * 16 + fr][0] = s;
      sred[wr][wc * 64 + n * 16 + fr][1] = ss;
    }
  }
  __syncthreads();
  if (t < 128) {
    const float s = sred[0][t][0] + sred[1][t][0];
    const float ss = sred[0][t][1] + sred[1][t][1];
    atomicAdd(&bna[c0 + t], s);
    atomicAdd(&bna[256 + c0 + t], ss);
  }
}

// ---------------------------------------------------------------- fused bias+attention, MFMA
// One block per (b,h), 512 threads = 8 waves, each wave owns 32 q-rows.
// Augmented GEMM: S = Q'K'^T with Q'=[q*scale, z], K'=[k, phi.z], Kdim=160.
__global__ __launch_bounds__(512, 2) void k_attn2(const short* __restrict__ qbf,
                                                  const short* __restrict__ kbf,
                                                  const short* __restrict__ vbf,
                                                  const short* __restrict__ zbf,
                                                  const float* __restrict__ phiAll,
                                                  short* __restrict__ obf, int l) {
  __shared__ __align__(16) char Ks[256 * 384];     // K'[256][192 bf16], XOR-swz 16B chunks
  __shared__ __align__(16) char Vt[32 * 512];      // V^T[32][256 bf16], XOR-swz
  __shared__ __align__(16) char Pw[8 * 2 * 2560];  // per-wave double-buffered P tile
  __shared__ float rs_l[8 * 32];
  __shared__ float ph2[128];
  const int t = threadIdx.x;
  const int bh = blockIdx.x;
  const int b = bh >> 3, hh = bh & 7;
  const int bnode = b * 256;

  if (t < 128)
    ph2[t] = phiAll[(((size_t)l * NB + b) * NH + hh) * QP + (t >> 1)];
  __syncthreads();
  {
    const int r = t >> 1, half = t & 1;
    const size_t rowbase = (size_t)(bnode + r) * 256 + hh * 32;
    // K' cols 0..31 = k slice (bf16 direct)
#pragma unroll
    for (int j2 = 0; j2 < 2; ++j2) {
      const int c = half * 2 + j2;
      short8v v = *(const short8v*)(kbf + rowbase + c * 8);
      *(short8v*)(Ks + r * 384 + ((c ^ (r & 7)) << 4)) = v;
    }
    // K' cols 32..159 = phi*z (zbf bf16 -> f32 mul -> bf16)
    const short* zrow = zbf + (size_t)(bnode + r) * 128 + half * 64;
#pragma unroll
    for (int cc = 0; cc < 8; ++cc) {
      const short8v zv = *(const short8v*)(zrow + cc * 8);
      const int zc = half * 64 + cc * 8;
      short8v o;
#pragma unroll
      for (int e = 0; e < 8; ++e)
        o[e] = f2b(b2f((unsigned short)zv[e]) * ph2[zc + e]);
      const int c = 4 + half * 8 + cc;
      *(short8v*)(Ks + r * 384 + ((c ^ (r & 7)) << 4)) = o;
    }
    // V^T staging (scalar transpose)
    const short* vrow = vbf + rowbase + half * 16;
    short8v v0 = *(const short8v*)(vrow);
    short8v v1 = *(const short8v*)(vrow + 8);
#pragma unroll
    for (int dd = 0; dd < 16; ++dd) {
      const int d = half * 16 + dd;
      const short val = dd < 8 ? v0[dd] : v1[dd - 8];
      *(short*)(Vt + d * 512 + (((r >> 3) ^ (d & 7)) << 4) + (r & 7) * 2) = val;
    }
  }
  __syncthreads();

  const int lane = t & 63, w = t >> 6;
  const int fr = lane & 15, fq = lane >> 4;
  const int i0w = w * 32;

  // Q' fragments in registers: Qf[s][ks]; ks0 = q slice, ks1..4 = plain z (bf16 direct)
  short8v Qf[2][5];
#pragma unroll
  for (int s = 0; s < 2; ++s) {
    const int node = bnode + i0w + s * 16 + fr;
    Qf[s][0] = *(const short8v*)(qbf + (size_t)node * 256 + hh * 32 + fq * 8);
    const short* zr = zbf + (size_t)node * 128;
#pragma unroll
    for (int ks = 1; ks < 5; ++ks)
      Qf[s][ks] = *(const short8v*)(zr + (ks - 1) * 32 + fq * 8);
  }

  // S^T = K' Q'^T : acc[s][jt] lane holds S[q = i0w+s*16+fr][j = jt*16+fq*4+rr]
  f32x4 acc[2][16] = {};
#pragma unroll
  for (int ks = 0; ks < 5; ++ks) {
#pragma unroll
    for (int jt = 0; jt < 16; ++jt) {
      const int row = jt * 16 + fr;
      const short8v a = *(const short8v*)(Ks + row * 384 + (((ks * 4 + fq) ^ (row & 7)) << 4));
      acc[0][jt] = __builtin_amdgcn_mfma_f32_16x16x32_bf16(a, Qf[0][ks], acc[0][jt], 0, 0, 0);
      acc[1][jt] = __builtin_amdgcn_mfma_f32_16x16x32_bf16(a, Qf[1][ks], acc[1][jt], 0, 0, 0);
    }
  }

  // softmax: row q is lane-local + reduce across fq lanes
  float rsv0, rsv1;
#pragma unroll
  for (int s = 0; s < 2; ++s) {
    float m = -1e30f;
#pragma unroll
    for (int jt = 0; jt < 16; ++jt)
#pragma unroll
      for (int rr = 0; rr < 4; ++rr) m = fmaxf(m, acc[s][jt][rr]);
    m = fmaxf(m, __shfl_xor(m, 16));
    m = fmaxf(m, __shfl_xor(m, 32));
    float sm = 0.f;
#pragma unroll
    for (int jt = 0; jt < 16; ++jt)
#pragma unroll
      for (int rr = 0; rr < 4; ++rr) {
        const float e = __expf(acc[s][jt][rr] - m);
        acc[s][jt][rr] = e;
        sm += e;
      }
    sm += __shfl_xor(sm, 16);
    sm += __shfl_xor(sm, 32);
    const float r = 1.0f / sm;
    if (s == 0) rsv0 = r; else rsv1 = r;
  }
  if (fq == 0) rs_l[w * 32 + fr] = rsv0;
  if (fq == 1) rs_l[w * 32 + 16 + fr] = rsv1;

  // PV: per 32-j step, round-trip P through double-buffered per-wave LDS
  f32x4 oac[2][2] = {};
  char* pw0 = Pw + w * 5120;
#pragma unroll
  for (int ks = 0; ks < 8; ++ks) {
    char* pw = pw0 + (ks & 1) * 2560;
#pragma unroll
    for (int s = 0; s < 2; ++s) {
#pragma unroll
      for (int j2 = 0; j2 < 2; ++j2) {
        const int jt = ks * 2 + j2;
        short4 pk;
        pk.x = f2b(acc[s][jt][0]); pk.y = f2b(acc[s][jt][1]);
        pk.z = f2b(acc[s][jt][2]); pk.w = f2b(acc[s][jt][3]);
        *(short4*)(pw + (s * 16 + fr) * 80 + j2 * 32 + fq * 8) = pk;
      }
    }
    asm volatile("s_waitcnt lgkmcnt(0)" ::: "memory");
    __builtin_amdgcn_sched_barrier(0);
    const short8v pa0 = *(const short8v*)(pw + fr * 80 + fq * 16);
    const short8v pa1 = *(const short8v*)(pw + (16 + fr) * 80 + fq * 16);
    const int sw = (((ks * 4 + fq) ^ (fr & 7)) << 4);
    const short8v vb0 = *(const short8v*)(Vt + fr * 512 + sw);
    const short8v vb1 = *(const short8v*)(Vt + (16 + fr) * 512 + sw);
    oac[0][0] = __builtin_amdgcn_mfma_f32_16x16x32_bf16(pa0, vb0, oac[0][0], 0, 0, 0);
    oac[0][1] = __builtin_amdgcn_mfma_f32_16x16x32_bf16(pa0, vb1, oac[0][1], 0, 0, 0);
    oac[1][0] = __builtin_amdgcn_mfma_f32_16x16x32_bf16(pa1, vb0, oac[1][0], 0, 0, 0);
    oac[1][1] = __builtin_amdgcn_mfma_f32_16x16x32_bf16(pa1, vb1, oac[1][1], 0, 0, 0);
  }

  // epilogue
#pragma unroll
  for (int s = 0; s < 2; ++s) {
#pragma unroll
    for (int rr = 0; rr < 4; ++rr) {
      const float rs = rs_l[w * 32 + s * 16 + fq * 4 + rr];
      const int node = bnode + i0w + s * 16 + fq * 4 + rr;
#pragma unroll
      for (int nt = 0; nt < 2; ++nt)
        obf[(size_t)node * 256 + hh * 32 + nt * 16 + fr] = f2b(oac[s][nt][rr] * rs);
    }
  }
}

// ---------------------------------------------------------------- BN apply (final layer -> out)
__global__ __launch_bounds__(256) void k_bn_apply(const float* __restrict__ h,
                                                  const float* __restrict__ accum,
                                                  const float* __restrict__ gamma,
                                                  const float* __restrict__ beta,
                                                  float* __restrict__ outp, int l) {
  const int idx = blockIdx.x * 256 + threadIdx.x;
  const int col = idx & 255;
  const float mean = accum[col] * (1.0f / NT);
  const float var = accum[DD + col] * (1.0f / NT) - mean * mean;
  const float rstd = rsqrtf(var + 1e-5f);
  outp[idx] = (h[idx] - mean) * rstd * gamma[l * DD + col] + beta[l * DD + col];
}

// ================================================================ host
extern "C" void kernel_launch(void* const* d_in, const int* in_sizes, int n_in,
                              void* d_out, int out_size, void* d_ws, size_t ws_size,
                              hipStream_t stream) {
  (void)in_sizes; (void)n_in; (void)out_size; (void)ws_size;
  const float* x    = (const float*)d_in[0];
  const float* z    = (const float*)d_in[1];
  const float* Lam  = (const float*)d_in[2];
  const float* Wq   = (const float*)d_in[4];
  const float* Wk   = (const float*)d_in[5];
  const float* Wv   = (const float*)d_in[6];
  const float* Wo   = (const float*)d_in[7];
  const float* bq   = (const float*)d_in[8];
  const float* bk   = (const float*)d_in[9];
  const float* bv   = (const float*)d_in[10];
  const float* bo   = (const float*)d_in[11];
  const float* pW1  = (const float*)d_in[12];
  const float* pb1  = (const float*)d_in[13];
  const float* pW2  = (const float*)d_in[14];
  const float* pb2  = (const float*)d_in[15];
  const float* gam  = (const float*)d_in[16];
  const float* bet  = (const float*)d_in[17];
  float* out = (float*)d_out;

  float* h    = (float*)d_ws;                 // 8 MB fp32 running h (pre-BN)
  short* qbf  = (short*)(h + HD2);            // 4 MB
  short* kbf  = qbf + HD2;
  short* vbf  = kbf + HD2;
  short* obf  = vbf + HD2;                    // attn out bf16
  short* zbf  = obf + HD2;                    // 2 MB bf16 z
  short* Wt   = zbf + NT * 128;               // 2 MB (16 mats x 256x256 bf16)
  float* phiA = (float*)(Wt + 16 * DD * DD);  // 32 KB
  float* bna  = phiA + 4 * NB * NH * QP;      // 4 layers x 512

  k_init<<<1024, 256, 0, stream>>>(z, out + HD2, zbf, bna);
  k_wt<<<dim3(16, 8), 256, 0, stream>>>(Wq, Wk, Wv, Wo, Wt);
  k_phi_all<<<dim3(8, 4), 256, 0, stream>>>(Lam, pW1, pb1, pW2, pb2, phiA);
  for (int l = 0; l < 4; ++l) {
    const float* bnprev = l ? bna + (l - 1) * 512 : nullptr;
    const float* gprev  = l ? gam + (l - 1) * DD : gam;
    const float* bprev  = l ? bet + (l - 1) * DD : bet;
    const float* hsrc   = l ? h : x;
    k_proj<<<dim3(64, 2, 3), 256, 0, stream>>>(hsrc, Wt + (size_t)l * 4 * DD * DD,
                                               bnprev, gprev, bprev,
                                               bq + l * DD, bk + l * DD, bv + l * DD,
                                               qbf, kbf, vbf);
    k_attn2<<<256, 512, 0, stream>>>(qbf, kbf, vbf, zbf, phiA, obf, l);
    k_projo<<<dim3(128, 2), 256, 0, stream>>>(obf, Wt + (size_t)(l * 4 + 3) * DD * DD,
                                              bo + l * DD, hsrc, h,
                                              bnprev, gprev, bprev, bna + l * 512);
  }
  k_bn_apply<<<8192, 256, 0, stream>>>(h, bna + 3 * 512, gam, bet, out, 3);
}